// Round 1
// baseline (355.890 us; speedup 1.0000x reference)
//
#include <hip/hip_runtime.h>
#include <math.h>

typedef unsigned short u16;
typedef __bf16 bf16x8 __attribute__((ext_vector_type(8)));
typedef float f32x4 __attribute__((ext_vector_type(4)));

#define T_TOKENS 4096   // B*S
#define D_DIM    512
#define H_DIM    2048
#define E_NUM    8
#define CAP      4096   // per-expert worst-case token capacity

__device__ __forceinline__ u16 f2bf(float f) {
  unsigned int u = __builtin_bit_cast(unsigned int, f);
  u = (u + 0x7fffu + ((u >> 16) & 1u)) >> 16;   // RNE
  return (u16)u;
}

// ---------------- f32 -> bf16 straight convert (x) ----------------
__global__ __launch_bounds__(256) void cvt_bf16_kernel(const float* __restrict__ in,
                                                       u16* __restrict__ out) {
  int i = blockIdx.x * 256 + threadIdx.x;   // over n/4
  float4 v = ((const float4*)in)[i];
  ushort4 o;
  o.x = f2bf(v.x); o.y = f2bf(v.y); o.z = f2bf(v.z); o.w = f2bf(v.w);
  ((ushort4*)out)[i] = o;
}

// ---------------- f32 [E][R][C] -> bf16 [E][C][R] transpose ----------------
__global__ __launch_bounds__(256) void transpose_bf16_kernel(const float* __restrict__ in,
                                                             u16* __restrict__ out,
                                                             int R, int C) {
  __shared__ float tile[32][33];
  const int e = blockIdx.z;
  const int c0 = blockIdx.x * 32, r0 = blockIdx.y * 32;
  const float* src = in + (size_t)e * R * C;
  u16* dst = out + (size_t)e * R * C;
  const int tx = threadIdx.x, ty = threadIdx.y;  // 32 x 8
#pragma unroll
  for (int i = 0; i < 4; i++)
    tile[ty + 8 * i][tx] = src[(size_t)(r0 + ty + 8 * i) * C + c0 + tx];
  __syncthreads();
#pragma unroll
  for (int i = 0; i < 4; i++)
    dst[(size_t)(c0 + ty + 8 * i) * R + r0 + tx] = f2bf(tile[tx][ty + 8 * i]);
}

// ---------------- router: logits, top-2, softmax ----------------
__global__ __launch_bounds__(256) void router_kernel(const float* __restrict__ x,
                                                     const float* __restrict__ rw,
                                                     const float* __restrict__ rb,
                                                     int* __restrict__ topk_idx,
                                                     float* __restrict__ topk_p) {
  const int lane = threadIdx.x & 63;
  const int t = blockIdx.x * 4 + (threadIdx.x >> 6);
  const float* xr = x + (size_t)t * D_DIM + lane * 8;
  float xv[8];
  *(float4*)(&xv[0]) = *(const float4*)(xr);
  *(float4*)(&xv[4]) = *(const float4*)(xr + 4);
  float acc[8] = {0.f,0.f,0.f,0.f,0.f,0.f,0.f,0.f};
#pragma unroll
  for (int j = 0; j < 8; j++) {
    const float4* w = (const float4*)(rw + (size_t)(lane * 8 + j) * E_NUM);
    float4 w0 = w[0], w1 = w[1];
    acc[0] += xv[j] * w0.x; acc[1] += xv[j] * w0.y;
    acc[2] += xv[j] * w0.z; acc[3] += xv[j] * w0.w;
    acc[4] += xv[j] * w1.x; acc[5] += xv[j] * w1.y;
    acc[6] += xv[j] * w1.z; acc[7] += xv[j] * w1.w;
  }
#pragma unroll
  for (int off = 32; off > 0; off >>= 1) {
#pragma unroll
    for (int e = 0; e < 8; e++) acc[e] += __shfl_down(acc[e], off);
  }
  if (lane == 0) {
    float l[8];
#pragma unroll
    for (int e = 0; e < 8; e++) l[e] = acc[e] + rb[e];
    int i0 = 0; float v0 = l[0];
#pragma unroll
    for (int e = 1; e < 8; e++) if (l[e] > v0) { v0 = l[e]; i0 = e; }
    int i1 = -1; float v1 = -3.4e38f;
#pragma unroll
    for (int e = 0; e < 8; e++) if (e != i0 && l[e] > v1) { v1 = l[e]; i1 = e; }
    float p1 = expf(v1 - v0);
    float s = 1.0f + p1;
    topk_idx[t * 2] = i0; topk_idx[t * 2 + 1] = i1;
    topk_p[t * 2] = 1.0f / s; topk_p[t * 2 + 1] = p1 / s;
  }
}

// ---------------- deterministic per-expert compaction ----------------
__global__ __launch_bounds__(256) void compact_kernel(const int* __restrict__ topk_idx,
                                                      const float* __restrict__ topk_p,
                                                      int* __restrict__ slot_list,
                                                      float* __restrict__ prob_list,
                                                      int* __restrict__ counts) {
  const int e = blockIdx.x;
  __shared__ int scan[256];
  __shared__ int sbase;
  if (threadIdx.x == 0) sbase = 0;
  __syncthreads();
  for (int c0 = 0; c0 < T_TOKENS; c0 += 256) {
    const int t = c0 + threadIdx.x;
    int flag = 0, slot = 0; float p = 0.f;
    int i0 = topk_idx[t * 2], i1 = topk_idx[t * 2 + 1];
    if (i0 == e)      { flag = 1; slot = t * 2;     p = topk_p[t * 2]; }
    else if (i1 == e) { flag = 1; slot = t * 2 + 1; p = topk_p[t * 2 + 1]; }
    scan[threadIdx.x] = flag;
    __syncthreads();
    for (int off = 1; off < 256; off <<= 1) {
      int v = (threadIdx.x >= off) ? scan[threadIdx.x - off] : 0;
      __syncthreads();
      scan[threadIdx.x] += v;
      __syncthreads();
    }
    int pos = sbase + scan[threadIdx.x] - 1;
    if (flag) { slot_list[e * CAP + pos] = slot; prob_list[e * CAP + pos] = p; }
    __syncthreads();
    if (threadIdx.x == 255) sbase += scan[255];
    __syncthreads();
  }
  if (threadIdx.x == 0) counts[e] = sbase;
}

// ---------------- grouped GEMM1: h = gelu(x @ w1 + b1) * p  (bf16 out) ----------------
// grid: (H/128, E*CAP/64); block 256 (4 waves 2x2); tile 64x128, BK=64
__global__ __launch_bounds__(256) void gemm1_kernel(const u16* __restrict__ xb,
                                                    const u16* __restrict__ w1t,   // [E][H][D]
                                                    const float* __restrict__ b1,  // [E][H]
                                                    const int* __restrict__ slot_list,
                                                    const float* __restrict__ prob_list,
                                                    const int* __restrict__ counts,
                                                    u16* __restrict__ hbuf) {      // [2T][H]
  const int e  = blockIdx.y >> 6;
  const int rt = blockIdx.y & 63;
  const int cnt = counts[e];
  const int rbase = rt * 64;
  if (rbase >= cnt) return;
  const int n0 = blockIdx.x * 128;

  __shared__ u16 At[64 * 64];
  __shared__ u16 Bt[128 * 64];

  const int tid = threadIdx.x;
  const int lane = tid & 63;
  const int wid = tid >> 6;
  const int wr = wid >> 1, wc = wid & 1;

  // A staging: thread covers row ar, 32B (2 x 16B chunks)
  const int ar = tid >> 2, aq = tid & 3;
  const int agrow = rbase + ar;
  int aslot = 0;
  if (agrow < cnt) aslot = slot_list[e * CAP + agrow];
  const u16* asrc = xb + (size_t)(aslot >> 1) * D_DIM + (aq << 4);
  u16* adst0 = &At[ar * 64 + (((aq * 2)     ^ (ar & 7)) << 3)];
  u16* adst1 = &At[ar * 64 + (((aq * 2 + 1) ^ (ar & 7)) << 3)];

  // B staging: thread covers row br, 64B (4 x 16B chunks)
  const int br = tid >> 1, bh = tid & 1;
  const u16* bsrc = w1t + ((size_t)e * H_DIM + n0 + br) * D_DIM + (bh << 5);
  u16* bdst[4];
#pragma unroll
  for (int j = 0; j < 4; j++)
    bdst[j] = &Bt[br * 64 + (((bh * 4 + j) ^ (br & 7)) << 3)];

  const int lrow = lane & 15, lk = lane >> 4;
  int arow[2], brow[4];
#pragma unroll
  for (int fr = 0; fr < 2; fr++) arow[fr] = wr * 32 + fr * 16 + lrow;
#pragma unroll
  for (int fc = 0; fc < 4; fc++) brow[fc] = wc * 64 + fc * 16 + lrow;

  f32x4 acc[2][4];
#pragma unroll
  for (int i = 0; i < 2; i++)
#pragma unroll
    for (int j = 0; j < 4; j++) acc[i][j] = (f32x4){0.f, 0.f, 0.f, 0.f};

  for (int k0 = 0; k0 < D_DIM; k0 += 64) {
    uint4 av0 = *(const uint4*)(asrc + k0);
    uint4 av1 = *(const uint4*)(asrc + k0 + 8);
    uint4 bv[4];
#pragma unroll
    for (int j = 0; j < 4; j++) bv[j] = *(const uint4*)(bsrc + k0 + j * 8);
    __syncthreads();
    *(uint4*)adst0 = av0;
    *(uint4*)adst1 = av1;
#pragma unroll
    for (int j = 0; j < 4; j++) *(uint4*)bdst[j] = bv[j];
    __syncthreads();
#pragma unroll
    for (int ks = 0; ks < 2; ks++) {
      const int c = ks * 4 + lk;
      bf16x8 afr[2], bfr[4];
#pragma unroll
      for (int fr = 0; fr < 2; fr++) {
        int r = arow[fr];
        afr[fr] = *(const bf16x8*)(&At[r * 64 + ((c ^ (r & 7)) << 3)]);
      }
#pragma unroll
      for (int fc = 0; fc < 4; fc++) {
        int n = brow[fc];
        bfr[fc] = *(const bf16x8*)(&Bt[n * 64 + ((c ^ (n & 7)) << 3)]);
      }
#pragma unroll
      for (int fr = 0; fr < 2; fr++)
#pragma unroll
        for (int fc = 0; fc < 4; fc++)
          acc[fr][fc] = __builtin_amdgcn_mfma_f32_16x16x32_bf16(afr[fr], bfr[fc], acc[fr][fc], 0, 0, 0);
    }
  }

  // epilogue: +b1, exact gelu, *p, bf16 store (scatter by slot)
#pragma unroll
  for (int fr = 0; fr < 2; fr++) {
#pragma unroll
    for (int reg = 0; reg < 4; reg++) {
      int rloc = wr * 32 + fr * 16 + lk * 4 + reg;
      int grow = rbase + rloc;
      if (grow < cnt) {
        int slot = slot_list[e * CAP + grow];
        float p  = prob_list[e * CAP + grow];
        size_t rowoff = (size_t)slot * H_DIM;
#pragma unroll
        for (int fc = 0; fc < 4; fc++) {
          int col = n0 + wc * 64 + fc * 16 + lrow;
          float v = acc[fr][fc][reg] + b1[e * H_DIM + col];
          float g = 0.5f * v * (1.0f + erff(v * 0.70710678118654752f));
          hbuf[rowoff + col] = f2bf(g * p);
        }
      }
    }
  }
}

// ---------------- grouped GEMM2: y = h @ w2 + p*b2  (f32 per-pair out) ----------------
// grid: (D/128, E*CAP/64)
__global__ __launch_bounds__(256) void gemm2_kernel(const u16* __restrict__ hbuf,   // [2T][H]
                                                    const u16* __restrict__ w2t,   // [E][D][H]
                                                    const float* __restrict__ b2,  // [E][D]
                                                    const int* __restrict__ slot_list,
                                                    const float* __restrict__ prob_list,
                                                    const int* __restrict__ counts,
                                                    float* __restrict__ ypairs) {  // [2T][D]
  const int e  = blockIdx.y >> 6;
  const int rt = blockIdx.y & 63;
  const int cnt = counts[e];
  const int rbase = rt * 64;
  if (rbase >= cnt) return;
  const int n0 = blockIdx.x * 128;

  __shared__ u16 At[64 * 64];
  __shared__ u16 Bt[128 * 64];

  const int tid = threadIdx.x;
  const int lane = tid & 63;
  const int wid = tid >> 6;
  const int wr = wid >> 1, wc = wid & 1;

  const int ar = tid >> 2, aq = tid & 3;
  const int agrow = rbase + ar;
  int aslot = 0;
  if (agrow < cnt) aslot = slot_list[e * CAP + agrow];
  const u16* asrc = hbuf + (size_t)aslot * H_DIM + (aq << 4);
  u16* adst0 = &At[ar * 64 + (((aq * 2)     ^ (ar & 7)) << 3)];
  u16* adst1 = &At[ar * 64 + (((aq * 2 + 1) ^ (ar & 7)) << 3)];

  const int br = tid >> 1, bh = tid & 1;
  const u16* bsrc = w2t + ((size_t)e * D_DIM + n0 + br) * H_DIM + (bh << 5);
  u16* bdst[4];
#pragma unroll
  for (int j = 0; j < 4; j++)
    bdst[j] = &Bt[br * 64 + (((bh * 4 + j) ^ (br & 7)) << 3)];

  const int lrow = lane & 15, lk = lane >> 4;
  int arow[2], brow[4];
#pragma unroll
  for (int fr = 0; fr < 2; fr++) arow[fr] = wr * 32 + fr * 16 + lrow;
#pragma unroll
  for (int fc = 0; fc < 4; fc++) brow[fc] = wc * 64 + fc * 16 + lrow;

  f32x4 acc[2][4];
#pragma unroll
  for (int i = 0; i < 2; i++)
#pragma unroll
    for (int j = 0; j < 4; j++) acc[i][j] = (f32x4){0.f, 0.f, 0.f, 0.f};

  for (int k0 = 0; k0 < H_DIM; k0 += 64) {
    uint4 av0 = *(const uint4*)(asrc + k0);
    uint4 av1 = *(const uint4*)(asrc + k0 + 8);
    uint4 bv[4];
#pragma unroll
    for (int j = 0; j < 4; j++) bv[j] = *(const uint4*)(bsrc + k0 + j * 8);
    __syncthreads();
    *(uint4*)adst0 = av0;
    *(uint4*)adst1 = av1;
#pragma unroll
    for (int j = 0; j < 4; j++) *(uint4*)bdst[j] = bv[j];
    __syncthreads();
#pragma unroll
    for (int ks = 0; ks < 2; ks++) {
      const int c = ks * 4 + lk;
      bf16x8 afr[2], bfr[4];
#pragma unroll
      for (int fr = 0; fr < 2; fr++) {
        int r = arow[fr];
        afr[fr] = *(const bf16x8*)(&At[r * 64 + ((c ^ (r & 7)) << 3)]);
      }
#pragma unroll
      for (int fc = 0; fc < 4; fc++) {
        int n = brow[fc];
        bfr[fc] = *(const bf16x8*)(&Bt[n * 64 + ((c ^ (n & 7)) << 3)]);
      }
#pragma unroll
      for (int fr = 0; fr < 2; fr++)
#pragma unroll
        for (int fc = 0; fc < 4; fc++)
          acc[fr][fc] = __builtin_amdgcn_mfma_f32_16x16x32_bf16(afr[fr], bfr[fc], acc[fr][fc], 0, 0, 0);
    }
  }

#pragma unroll
  for (int fr = 0; fr < 2; fr++) {
#pragma unroll
    for (int reg = 0; reg < 4; reg++) {
      int rloc = wr * 32 + fr * 16 + lk * 4 + reg;
      int grow = rbase + rloc;
      if (grow < cnt) {
        int slot = slot_list[e * CAP + grow];
        float p  = prob_list[e * CAP + grow];
        size_t rowoff = (size_t)slot * D_DIM;
#pragma unroll
        for (int fc = 0; fc < 4; fc++) {
          int col = n0 + wc * 64 + fc * 16 + lrow;
          ypairs[rowoff + col] = acc[fr][fc][reg] + p * b2[e * D_DIM + col];
        }
      }
    }
  }
}

// ---------------- combine: out[t] = y[2t] + y[2t+1] ----------------
__global__ __launch_bounds__(256) void combine_kernel(const float* __restrict__ yp,
                                                      float* __restrict__ out) {
  int i = blockIdx.x * 256 + threadIdx.x;   // over T*D/4
  int t = i >> 7;          // D/4 = 128
  int dq = i & 127;
  float4 a = ((const float4*)(yp + (size_t)(t * 2) * D_DIM))[dq];
  float4 b = ((const float4*)(yp + (size_t)(t * 2 + 1) * D_DIM))[dq];
  float4 r;
  r.x = a.x + b.x; r.y = a.y + b.y; r.z = a.z + b.z; r.w = a.w + b.w;
  ((float4*)(out + (size_t)t * D_DIM))[dq] = r;
}

extern "C" void kernel_launch(void* const* d_in, const int* in_sizes, int n_in,
                              void* d_out, int out_size, void* d_ws, size_t ws_size,
                              hipStream_t stream) {
  const float* x  = (const float*)d_in[0];
  const float* w1 = (const float*)d_in[1];
  const float* w2 = (const float*)d_in[2];
  const float* b1 = (const float*)d_in[3];
  const float* b2 = (const float*)d_in[4];
  const float* rw = (const float*)d_in[5];
  const float* rb = (const float*)d_in[6];
  float* out = (float*)d_out;

  char* ws = (char*)d_ws;
  size_t off = 0;
  auto alloc = [&](size_t bytes) -> void* {
    void* p = ws + off;
    off = (off + bytes + 255) & ~(size_t)255;
    return p;
  };
  int*   counts    = (int*)alloc(E_NUM * 4);
  int*   slot_list = (int*)alloc((size_t)E_NUM * CAP * 4);
  float* prob_list = (float*)alloc((size_t)E_NUM * CAP * 4);
  int*   topk_idx  = (int*)alloc((size_t)T_TOKENS * 2 * 4);
  float* topk_p    = (float*)alloc((size_t)T_TOKENS * 2 * 4);
  u16*   xb        = (u16*)alloc((size_t)T_TOKENS * D_DIM * 2);
  u16*   w1t       = (u16*)alloc((size_t)E_NUM * H_DIM * D_DIM * 2);
  u16*   w2t       = (u16*)alloc((size_t)E_NUM * H_DIM * D_DIM * 2);
  u16*   hbuf      = (u16*)alloc((size_t)T_TOKENS * 2 * H_DIM * 2);
  float* ypairs    = (float*)alloc((size_t)T_TOKENS * 2 * D_DIM * 4);

  cvt_bf16_kernel<<<(T_TOKENS * D_DIM / 4) / 256, 256, 0, stream>>>(x, xb);
  transpose_bf16_kernel<<<dim3(H_DIM / 32, D_DIM / 32, E_NUM), dim3(32, 8), 0, stream>>>(w1, w1t, D_DIM, H_DIM);
  transpose_bf16_kernel<<<dim3(D_DIM / 32, H_DIM / 32, E_NUM), dim3(32, 8), 0, stream>>>(w2, w2t, H_DIM, D_DIM);
  router_kernel<<<T_TOKENS / 4, 256, 0, stream>>>(x, rw, rb, topk_idx, topk_p);
  compact_kernel<<<E_NUM, 256, 0, stream>>>(topk_idx, topk_p, slot_list, prob_list, counts);
  gemm1_kernel<<<dim3(H_DIM / 128, E_NUM * (CAP / 64)), 256, 0, stream>>>(xb, w1t, b1, slot_list, prob_list, counts, hbuf);
  gemm2_kernel<<<dim3(D_DIM / 128, E_NUM * (CAP / 64)), 256, 0, stream>>>(hbuf, w2t, b2, slot_list, prob_list, counts, ypairs);
  combine_kernel<<<(T_TOKENS * D_DIM / 4) / 256, 256, 0, stream>>>(ypairs, out);
}

// Round 2
// 174.552 us; speedup vs baseline: 2.0389x; 2.0389x over previous
//
#include <hip/hip_runtime.h>
#include <math.h>

typedef unsigned short u16;
typedef __bf16 bf16x8 __attribute__((ext_vector_type(8)));
typedef float f32x4 __attribute__((ext_vector_type(4)));

#define T_TOKENS 4096   // B*S
#define D_DIM    512
#define H_DIM    2048
#define E_NUM    8
#define CAP      4096   // per-expert worst-case capacity (lists only)
#define NSLOT    (T_TOKENS * 2)

__device__ __forceinline__ u16 f2bf(float f) {
  unsigned int u = __builtin_bit_cast(unsigned int, f);
  u = (u + 0x7fffu + ((u >> 16) & 1u)) >> 16;   // RNE
  return (u16)u;
}

__device__ __forceinline__ void gload16(const void* g, void* l) {
  __builtin_amdgcn_global_load_lds(
      (__attribute__((address_space(1))) void*)(g),
      (__attribute__((address_space(3))) void*)(l), 16, 0, 0);
}

// ---------------- f32 -> bf16 straight convert (x) ----------------
__global__ __launch_bounds__(256) void cvt_bf16_kernel(const float* __restrict__ in,
                                                       u16* __restrict__ out) {
  int i = blockIdx.x * 256 + threadIdx.x;   // over n/4
  float4 v = ((const float4*)in)[i];
  ushort4 o;
  o.x = f2bf(v.x); o.y = f2bf(v.y); o.z = f2bf(v.z); o.w = f2bf(v.w);
  ((ushort4*)out)[i] = o;
}

// ---------------- f32 [E][R][C] -> bf16 [E][C][R] transpose ----------------
__global__ __launch_bounds__(256) void transpose_bf16_kernel(const float* __restrict__ in,
                                                             u16* __restrict__ out,
                                                             int R, int C) {
  __shared__ float tile[32][33];
  const int e = blockIdx.z;
  const int c0 = blockIdx.x * 32, r0 = blockIdx.y * 32;
  const float* src = in + (size_t)e * R * C;
  u16* dst = out + (size_t)e * R * C;
  const int tx = threadIdx.x, ty = threadIdx.y;  // 32 x 8
#pragma unroll
  for (int i = 0; i < 4; i++)
    tile[ty + 8 * i][tx] = src[(size_t)(r0 + ty + 8 * i) * C + c0 + tx];
  __syncthreads();
#pragma unroll
  for (int i = 0; i < 4; i++)
    dst[(size_t)(c0 + ty + 8 * i) * R + r0 + tx] = f2bf(tile[tx][ty + 8 * i]);
}

// ---------------- router: logits, top-2, softmax ----------------
__global__ __launch_bounds__(256) void router_kernel(const float* __restrict__ x,
                                                     const float* __restrict__ rw,
                                                     const float* __restrict__ rb,
                                                     int* __restrict__ topk_idx,
                                                     float* __restrict__ topk_p) {
  const int lane = threadIdx.x & 63;
  const int t = blockIdx.x * 4 + (threadIdx.x >> 6);
  const float* xr = x + (size_t)t * D_DIM + lane * 8;
  float xv[8];
  *(float4*)(&xv[0]) = *(const float4*)(xr);
  *(float4*)(&xv[4]) = *(const float4*)(xr + 4);
  float acc[8] = {0.f,0.f,0.f,0.f,0.f,0.f,0.f,0.f};
#pragma unroll
  for (int j = 0; j < 8; j++) {
    const float4* w = (const float4*)(rw + (size_t)(lane * 8 + j) * E_NUM);
    float4 w0 = w[0], w1 = w[1];
    acc[0] += xv[j] * w0.x; acc[1] += xv[j] * w0.y;
    acc[2] += xv[j] * w0.z; acc[3] += xv[j] * w0.w;
    acc[4] += xv[j] * w1.x; acc[5] += xv[j] * w1.y;
    acc[6] += xv[j] * w1.z; acc[7] += xv[j] * w1.w;
  }
#pragma unroll
  for (int off = 32; off > 0; off >>= 1) {
#pragma unroll
    for (int e = 0; e < 8; e++) acc[e] += __shfl_down(acc[e], off);
  }
  if (lane == 0) {
    float l[8];
#pragma unroll
    for (int e = 0; e < 8; e++) l[e] = acc[e] + rb[e];
    int i0 = 0; float v0 = l[0];
#pragma unroll
    for (int e = 1; e < 8; e++) if (l[e] > v0) { v0 = l[e]; i0 = e; }
    int i1 = -1; float v1 = -3.4e38f;
#pragma unroll
    for (int e = 0; e < 8; e++) if (e != i0 && l[e] > v1) { v1 = l[e]; i1 = e; }
    float p1 = expf(v1 - v0);
    float s = 1.0f + p1;
    topk_idx[t * 2] = i0; topk_idx[t * 2 + 1] = i1;
    topk_p[t * 2] = 1.0f / s; topk_p[t * 2 + 1] = p1 / s;
  }
}

// ---------------- deterministic per-expert compaction (ballot scan) ----------------
__global__ __launch_bounds__(256) void compact_kernel(const int* __restrict__ topk_idx,
                                                      const float* __restrict__ topk_p,
                                                      int* __restrict__ slot_list,
                                                      float* __restrict__ prob_list,
                                                      int* __restrict__ counts) {
  const int e = blockIdx.x;
  const int tid = threadIdx.x, lane = tid & 63, w = tid >> 6;
  __shared__ int wsum[4];
  __shared__ int sbase;
  if (tid == 0) sbase = 0;
  __syncthreads();
  for (int c0 = 0; c0 < T_TOKENS; c0 += 256) {
    const int t = c0 + tid;
    const int i0 = topk_idx[t * 2], i1 = topk_idx[t * 2 + 1];
    int flag = 0, slot = 0; float p = 0.f;
    if (i0 == e)      { flag = 1; slot = t * 2;     p = topk_p[t * 2]; }
    else if (i1 == e) { flag = 1; slot = t * 2 + 1; p = topk_p[t * 2 + 1]; }
    unsigned long long m = __ballot(flag);
    if (lane == 0) wsum[w] = (int)__popcll(m);
    const int wpre = (int)__popcll(m & ((1ull << lane) - 1ull));
    __syncthreads();
    int base = sbase;
#pragma unroll
    for (int j = 0; j < 4; j++) if (j < w) base += wsum[j];
    const int tot = wsum[0] + wsum[1] + wsum[2] + wsum[3];
    if (flag) { slot_list[e * CAP + base + wpre] = slot; prob_list[e * CAP + base + wpre] = p; }
    __syncthreads();
    if (tid == 0) sbase += tot;
  }
  __syncthreads();
  if (tid == 0) counts[e] = sbase;
}

// ---------------- grouped GEMM1: h = gelu(x @ w1 + b1) * p  (bf16, by slot) ----------------
// tile 128x128, BK=64, 4 waves (2x2, 64x64 each), global_load_lds staging
// grid: (H/128=16, E*16)
__global__ __launch_bounds__(256) void gemm1_kernel(const u16* __restrict__ xb,
                                                    const u16* __restrict__ w1t,   // [E][H][D]
                                                    const float* __restrict__ b1,  // [E][H]
                                                    const int* __restrict__ slot_list,
                                                    const float* __restrict__ prob_list,
                                                    const int* __restrict__ counts,
                                                    u16* __restrict__ hbuf) {      // [2T][H]
  const int e  = blockIdx.y >> 4;
  const int rt = blockIdx.y & 15;
  const int cnt = counts[e];
  const int rbase = rt * 128;
  if (rbase >= cnt) return;
  const int n0 = blockIdx.x * 128;

  __shared__ __align__(16) u16 At[128 * 64];
  __shared__ __align__(16) u16 Bt[128 * 64];

  const int tid = threadIdx.x, lane = tid & 63, wid = tid >> 6;
  const int wr = wid >> 1, wc = wid & 1;
  const int lr8 = lane >> 3, kc = (lane & 7) * 8;
  const int lrow = lane & 15, lk = lane >> 4;

  const u16* pa[4]; const u16* pb[4]; u16* la[4]; u16* lb[4];
#pragma unroll
  for (int i = 0; i < 4; i++) {
    const int row = (wid * 4 + i) * 8 + lr8;         // 0..127
    const int grow = rbase + row;
    int tok = 0;
    if (grow < cnt) tok = slot_list[e * CAP + grow] >> 1;
    pa[i] = xb + (size_t)tok * D_DIM + kc;
    la[i] = At + (wid * 4 + i) * 512;                 // wave-uniform
    pb[i] = w1t + ((size_t)e * H_DIM + n0 + row) * D_DIM + kc;
    lb[i] = Bt + (wid * 4 + i) * 512;
  }

  f32x4 acc[4][4];
#pragma unroll
  for (int i = 0; i < 4; i++)
#pragma unroll
    for (int j = 0; j < 4; j++) acc[i][j] = (f32x4){0.f, 0.f, 0.f, 0.f};

  for (int k0 = 0; k0 < D_DIM; k0 += 64) {
#pragma unroll
    for (int i = 0; i < 4; i++) gload16(pa[i] + k0, la[i]);
#pragma unroll
    for (int i = 0; i < 4; i++) gload16(pb[i] + k0, lb[i]);
    __syncthreads();   // compiler drains vmcnt(0) before s_barrier -> tile resident
#pragma unroll
    for (int ks = 0; ks < 2; ks++) {
      bf16x8 afr[4], bfr[4];
#pragma unroll
      for (int f = 0; f < 4; f++) {
        afr[f] = *(const bf16x8*)(At + (wr * 64 + f * 16 + lrow) * 64 + ks * 32 + lk * 8);
        bfr[f] = *(const bf16x8*)(Bt + (wc * 64 + f * 16 + lrow) * 64 + ks * 32 + lk * 8);
      }
#pragma unroll
      for (int fr = 0; fr < 4; fr++)
#pragma unroll
        for (int fc = 0; fc < 4; fc++)
          acc[fr][fc] = __builtin_amdgcn_mfma_f32_16x16x32_bf16(afr[fr], bfr[fc], acc[fr][fc], 0, 0, 0);
    }
    __syncthreads();
  }

  float bias[4];
#pragma unroll
  for (int fc = 0; fc < 4; fc++) bias[fc] = b1[e * H_DIM + n0 + wc * 64 + fc * 16 + lrow];
#pragma unroll
  for (int fr = 0; fr < 4; fr++) {
#pragma unroll
    for (int reg = 0; reg < 4; reg++) {
      const int rloc = wr * 64 + fr * 16 + lk * 4 + reg;
      const int grow = rbase + rloc;
      if (grow < cnt) {
        const int slot = slot_list[e * CAP + grow];
        const float p  = prob_list[e * CAP + grow];
        u16* dst = hbuf + (size_t)slot * H_DIM + n0 + wc * 64 + lrow;
#pragma unroll
        for (int fc = 0; fc < 4; fc++) {
          float v = acc[fr][fc][reg] + bias[fc];
          float g = 0.5f * v * (1.0f + erff(v * 0.70710678118654752f));
          dst[fc * 16] = f2bf(g * p);
        }
      }
    }
  }
}

// ---------------- grouped GEMM2: y_part = (h @ w2[kslice]) (+ p*b2 on s==0) ----------------
// tile 64x128, BK=64, split-K=2, 4 waves (2x2, 32x64 each), global_load_lds staging
// grid: (D/128=4, E*32, 2)
__global__ __launch_bounds__(256) void gemm2_kernel(const u16* __restrict__ hbuf,  // [2T][H]
                                                    const u16* __restrict__ w2t,   // [E][D][H]
                                                    const float* __restrict__ b2,  // [E][D]
                                                    const int* __restrict__ slot_list,
                                                    const float* __restrict__ prob_list,
                                                    const int* __restrict__ counts,
                                                    float* __restrict__ ypart) {   // [2][2T][D]
  const int e  = blockIdx.y >> 5;
  const int rt = blockIdx.y & 31;
  const int s  = blockIdx.z;
  const int cnt = counts[e];
  const int rbase = rt * 64;
  if (rbase >= cnt) return;
  const int n0 = blockIdx.x * 128;
  const int kb = s * (H_DIM / 2);

  __shared__ __align__(16) u16 At[64 * 64];
  __shared__ __align__(16) u16 Bt[128 * 64];

  const int tid = threadIdx.x, lane = tid & 63, wid = tid >> 6;
  const int wr = wid >> 1, wc = wid & 1;
  const int lr8 = lane >> 3, kc = (lane & 7) * 8;
  const int lrow = lane & 15, lk = lane >> 4;

  const u16* pa[2]; u16* la[2];
#pragma unroll
  for (int i = 0; i < 2; i++) {
    const int row = (wid * 2 + i) * 8 + lr8;          // 0..63
    const int grow = rbase + row;
    int slot = 0;
    if (grow < cnt) slot = slot_list[e * CAP + grow];
    pa[i] = hbuf + (size_t)slot * H_DIM + kb + kc;
    la[i] = At + (wid * 2 + i) * 512;
  }
  const u16* pb[4]; u16* lb[4];
#pragma unroll
  for (int i = 0; i < 4; i++) {
    const int row = (wid * 4 + i) * 8 + lr8;          // 0..127
    pb[i] = w2t + ((size_t)e * D_DIM + n0 + row) * H_DIM + kb + kc;
    lb[i] = Bt + (wid * 4 + i) * 512;
  }

  f32x4 acc[2][4];
#pragma unroll
  for (int i = 0; i < 2; i++)
#pragma unroll
    for (int j = 0; j < 4; j++) acc[i][j] = (f32x4){0.f, 0.f, 0.f, 0.f};

  for (int k0 = 0; k0 < H_DIM / 2; k0 += 64) {
#pragma unroll
    for (int i = 0; i < 2; i++) gload16(pa[i] + k0, la[i]);
#pragma unroll
    for (int i = 0; i < 4; i++) gload16(pb[i] + k0, lb[i]);
    __syncthreads();
#pragma unroll
    for (int ks = 0; ks < 2; ks++) {
      bf16x8 afr[2], bfr[4];
#pragma unroll
      for (int f = 0; f < 2; f++)
        afr[f] = *(const bf16x8*)(At + (wr * 32 + f * 16 + lrow) * 64 + ks * 32 + lk * 8);
#pragma unroll
      for (int f = 0; f < 4; f++)
        bfr[f] = *(const bf16x8*)(Bt + (wc * 64 + f * 16 + lrow) * 64 + ks * 32 + lk * 8);
#pragma unroll
      for (int fr = 0; fr < 2; fr++)
#pragma unroll
        for (int fc = 0; fc < 4; fc++)
          acc[fr][fc] = __builtin_amdgcn_mfma_f32_16x16x32_bf16(afr[fr], bfr[fc], acc[fr][fc], 0, 0, 0);
    }
    __syncthreads();
  }

#pragma unroll
  for (int fr = 0; fr < 2; fr++) {
#pragma unroll
    for (int reg = 0; reg < 4; reg++) {
      const int rloc = wr * 32 + fr * 16 + lk * 4 + reg;
      const int grow = rbase + rloc;
      if (grow < cnt) {
        const int slot = slot_list[e * CAP + grow];
        const float p  = prob_list[e * CAP + grow];
        float* dst = ypart + ((size_t)s * NSLOT + slot) * D_DIM + n0 + wc * 64 + lrow;
#pragma unroll
        for (int fc = 0; fc < 4; fc++) {
          float v = acc[fr][fc][reg];
          if (s == 0) v += p * b2[e * D_DIM + n0 + wc * 64 + fc * 16 + lrow];
          dst[fc * 16] = v;
        }
      }
    }
  }
}

// ---------------- combine: out[t] = sum over 2 slots x 2 K-splits ----------------
__global__ __launch_bounds__(256) void combine_kernel(const float* __restrict__ yp,
                                                      float* __restrict__ out) {
  int i = blockIdx.x * 256 + threadIdx.x;   // over T*D/4
  int t = i >> 7;          // D/4 = 128
  int dq = i & 127;
  float4 a = ((const float4*)(yp + (size_t)(t * 2) * D_DIM))[dq];
  float4 b = ((const float4*)(yp + (size_t)(t * 2 + 1) * D_DIM))[dq];
  float4 c = ((const float4*)(yp + ((size_t)NSLOT + t * 2) * D_DIM))[dq];
  float4 d = ((const float4*)(yp + ((size_t)NSLOT + t * 2 + 1) * D_DIM))[dq];
  float4 r;
  r.x = a.x + b.x + c.x + d.x;
  r.y = a.y + b.y + c.y + d.y;
  r.z = a.z + b.z + c.z + d.z;
  r.w = a.w + b.w + c.w + d.w;
  ((float4*)(out + (size_t)t * D_DIM))[dq] = r;
}

extern "C" void kernel_launch(void* const* d_in, const int* in_sizes, int n_in,
                              void* d_out, int out_size, void* d_ws, size_t ws_size,
                              hipStream_t stream) {
  const float* x  = (const float*)d_in[0];
  const float* w1 = (const float*)d_in[1];
  const float* w2 = (const float*)d_in[2];
  const float* b1 = (const float*)d_in[3];
  const float* b2 = (const float*)d_in[4];
  const float* rw = (const float*)d_in[5];
  const float* rb = (const float*)d_in[6];
  float* out = (float*)d_out;

  char* ws = (char*)d_ws;
  size_t off = 0;
  auto alloc = [&](size_t bytes) -> void* {
    void* p = ws + off;
    off = (off + bytes + 255) & ~(size_t)255;
    return p;
  };
  int*   counts    = (int*)alloc(E_NUM * 4);
  int*   slot_list = (int*)alloc((size_t)E_NUM * CAP * 4);
  float* prob_list = (float*)alloc((size_t)E_NUM * CAP * 4);
  int*   topk_idx  = (int*)alloc((size_t)T_TOKENS * 2 * 4);
  float* topk_p    = (float*)alloc((size_t)T_TOKENS * 2 * 4);
  u16*   xb        = (u16*)alloc((size_t)T_TOKENS * D_DIM * 2);
  u16*   w1t       = (u16*)alloc((size_t)E_NUM * H_DIM * D_DIM * 2);
  u16*   w2t       = (u16*)alloc((size_t)E_NUM * H_DIM * D_DIM * 2);
  u16*   hbuf      = (u16*)alloc((size_t)NSLOT * H_DIM * 2);
  float* ypart     = (float*)alloc((size_t)2 * NSLOT * D_DIM * 4);

  cvt_bf16_kernel<<<(T_TOKENS * D_DIM / 4) / 256, 256, 0, stream>>>(x, xb);
  transpose_bf16_kernel<<<dim3(H_DIM / 32, D_DIM / 32, E_NUM), dim3(32, 8), 0, stream>>>(w1, w1t, D_DIM, H_DIM);
  transpose_bf16_kernel<<<dim3(D_DIM / 32, H_DIM / 32, E_NUM), dim3(32, 8), 0, stream>>>(w2, w2t, H_DIM, D_DIM);
  router_kernel<<<T_TOKENS / 4, 256, 0, stream>>>(x, rw, rb, topk_idx, topk_p);
  compact_kernel<<<E_NUM, 256, 0, stream>>>(topk_idx, topk_p, slot_list, prob_list, counts);
  gemm1_kernel<<<dim3(H_DIM / 128, E_NUM * 16), 256, 0, stream>>>(xb, w1t, b1, slot_list, prob_list, counts, hbuf);
  gemm2_kernel<<<dim3(D_DIM / 128, E_NUM * 32, 2), 256, 0, stream>>>(hbuf, w2t, b2, slot_list, prob_list, counts, ypart);
  combine_kernel<<<(T_TOKENS * D_DIM / 4) / 256, 256, 0, stream>>>(ypart, out);
}

// Round 3
// 145.237 us; speedup vs baseline: 2.4504x; 1.2018x over previous
//
#include <hip/hip_runtime.h>
#include <math.h>

typedef unsigned short u16;
typedef __bf16 bf16x8 __attribute__((ext_vector_type(8)));
typedef float f32x4 __attribute__((ext_vector_type(4)));

#define T_TOKENS 4096   // B*S
#define D_DIM    512
#define H_DIM    2048
#define E_NUM    8
#define CAP      4096   // per-expert worst-case capacity
#define NSLOT    (T_TOKENS * 2)

__device__ __forceinline__ u16 f2bf(float f) {
  unsigned int u = __builtin_bit_cast(unsigned int, f);
  u = (u + 0x7fffu + ((u >> 16) & 1u)) >> 16;   // RNE
  return (u16)u;
}

__device__ __forceinline__ void gload16(const void* g, void* l) {
  __builtin_amdgcn_global_load_lds(
      (__attribute__((address_space(1))) void*)(g),
      (__attribute__((address_space(3))) void*)(l), 16, 0, 0);
}

// gelu(v) ~= v * sigmoid(v*(1.59576912 + 0.071354817*v^2))  (tanh-form, |err|<~3e-4)
__device__ __forceinline__ float gelu_fast(float v) {
  float u = v * __fmaf_rn(0.071354817f, v * v, 1.59576912f);
  return v / (1.0f + __expf(-u));
}

// ---------------- f32 [E][R][C] -> bf16 [E][C][R] transpose ----------------
__global__ __launch_bounds__(256) void transpose_bf16_kernel(const float* __restrict__ in,
                                                             u16* __restrict__ out,
                                                             int R, int C) {
  __shared__ float tile[32][33];
  const int e = blockIdx.z;
  const int c0 = blockIdx.x * 32, r0 = blockIdx.y * 32;
  const float* src = in + (size_t)e * R * C;
  u16* dst = out + (size_t)e * R * C;
  const int tx = threadIdx.x, ty = threadIdx.y;  // 32 x 8
#pragma unroll
  for (int i = 0; i < 4; i++)
    tile[ty + 8 * i][tx] = src[(size_t)(r0 + ty + 8 * i) * C + c0 + tx];
  __syncthreads();
#pragma unroll
  for (int i = 0; i < 4; i++)
    dst[(size_t)(c0 + ty + 8 * i) * R + r0 + tx] = f2bf(tile[tx][ty + 8 * i]);
}

// ---------------- router + x->bf16: logits, top-2, softmax ----------------
__global__ __launch_bounds__(256) void router_kernel(const float* __restrict__ x,
                                                     const float* __restrict__ rw,
                                                     const float* __restrict__ rb,
                                                     int* __restrict__ topk_idx,
                                                     float* __restrict__ topk_p,
                                                     u16* __restrict__ xb) {
  const int lane = threadIdx.x & 63;
  const int t = blockIdx.x * 4 + (threadIdx.x >> 6);
  const float* xr = x + (size_t)t * D_DIM + lane * 8;
  float xv[8];
  *(float4*)(&xv[0]) = *(const float4*)(xr);
  *(float4*)(&xv[4]) = *(const float4*)(xr + 4);
  // fused convert-out
  ushort4 o0, o1;
  o0.x = f2bf(xv[0]); o0.y = f2bf(xv[1]); o0.z = f2bf(xv[2]); o0.w = f2bf(xv[3]);
  o1.x = f2bf(xv[4]); o1.y = f2bf(xv[5]); o1.z = f2bf(xv[6]); o1.w = f2bf(xv[7]);
  ushort4* xo = (ushort4*)(xb + (size_t)t * D_DIM + lane * 8);
  xo[0] = o0; xo[1] = o1;

  float acc[8] = {0.f,0.f,0.f,0.f,0.f,0.f,0.f,0.f};
#pragma unroll
  for (int j = 0; j < 8; j++) {
    const float4* w = (const float4*)(rw + (size_t)(lane * 8 + j) * E_NUM);
    float4 w0 = w[0], w1 = w[1];
    acc[0] += xv[j] * w0.x; acc[1] += xv[j] * w0.y;
    acc[2] += xv[j] * w0.z; acc[3] += xv[j] * w0.w;
    acc[4] += xv[j] * w1.x; acc[5] += xv[j] * w1.y;
    acc[6] += xv[j] * w1.z; acc[7] += xv[j] * w1.w;
  }
#pragma unroll
  for (int off = 32; off > 0; off >>= 1) {
#pragma unroll
    for (int e = 0; e < 8; e++) acc[e] += __shfl_down(acc[e], off);
  }
  if (lane == 0) {
    float l[8];
#pragma unroll
    for (int e = 0; e < 8; e++) l[e] = acc[e] + rb[e];
    int i0 = 0; float v0 = l[0];
#pragma unroll
    for (int e = 1; e < 8; e++) if (l[e] > v0) { v0 = l[e]; i0 = e; }
    int i1 = -1; float v1 = -3.4e38f;
#pragma unroll
    for (int e = 0; e < 8; e++) if (e != i0 && l[e] > v1) { v1 = l[e]; i1 = e; }
    float p1 = expf(v1 - v0);
    float s = 1.0f + p1;
    topk_idx[t * 2] = i0; topk_idx[t * 2 + 1] = i1;
    topk_p[t * 2] = 1.0f / s; topk_p[t * 2 + 1] = p1 / s;
  }
}

// ---------------- deterministic per-expert compaction (ballot scan) ----------------
__global__ __launch_bounds__(256) void compact_kernel(const int* __restrict__ topk_idx,
                                                      const float* __restrict__ topk_p,
                                                      int* __restrict__ slot_list,
                                                      float* __restrict__ prob_list,
                                                      int* __restrict__ counts) {
  const int e = blockIdx.x;
  const int tid = threadIdx.x, lane = tid & 63, w = tid >> 6;
  __shared__ int wsum[4];
  __shared__ int sbase;
  if (tid == 0) sbase = 0;
  __syncthreads();
  for (int c0 = 0; c0 < T_TOKENS; c0 += 256) {
    const int t = c0 + tid;
    const int i0 = topk_idx[t * 2], i1 = topk_idx[t * 2 + 1];
    int flag = 0, slot = 0; float p = 0.f;
    if (i0 == e)      { flag = 1; slot = t * 2;     p = topk_p[t * 2]; }
    else if (i1 == e) { flag = 1; slot = t * 2 + 1; p = topk_p[t * 2 + 1]; }
    unsigned long long m = __ballot(flag);
    if (lane == 0) wsum[w] = (int)__popcll(m);
    const int wpre = (int)__popcll(m & ((1ull << lane) - 1ull));
    __syncthreads();
    int base = sbase;
#pragma unroll
    for (int j = 0; j < 4; j++) if (j < w) base += wsum[j];
    const int tot = wsum[0] + wsum[1] + wsum[2] + wsum[3];
    if (flag) { slot_list[e * CAP + base + wpre] = slot; prob_list[e * CAP + base + wpre] = p; }
    __syncthreads();
    if (tid == 0) sbase += tot;
  }
  __syncthreads();
  if (tid == 0) counts[e] = sbase;
}

// ---------------- grouped GEMM1: h = gelu(x @ w1 + b1) * p  (bf16, by slot) ----------------
// tile 128x128, BK=64, dbuf 2-phase pipeline, T2 swizzle (pre-permuted source)
// grid: (H/128=16, E*32)
__global__ __launch_bounds__(256) void gemm1_kernel(const u16* __restrict__ xb,
                                                    const u16* __restrict__ w1t,   // [E][H][D]
                                                    const float* __restrict__ b1,  // [E][H]
                                                    const int* __restrict__ slot_list,
                                                    const float* __restrict__ prob_list,
                                                    const int* __restrict__ counts,
                                                    u16* __restrict__ hbuf) {      // [2T][H]
  const int e  = blockIdx.y >> 5;
  const int rt = blockIdx.y & 31;
  const int cnt = counts[e];
  const int rbase = rt * 128;
  if (rbase >= cnt) return;
  const int n0 = blockIdx.x * 128;

  __shared__ __align__(16) u16 At[2][128 * 64];
  __shared__ __align__(16) u16 Bt[2][128 * 64];

  const int tid = threadIdx.x, lane = tid & 63, wid = tid >> 6;
  const int wr = wid >> 1, wc = wid & 1;
  const int lr8 = lane >> 3;
  const int sx = lane & 7;                     // swizzle key (read side)
  const int kperm = (sx ^ lr8) * 8;            // pre-permuted source chunk (stage side)
  const int lrow = lane & 15, lk = lane >> 4;

  const u16* pa[4]; const u16* pb[4]; int lo[4];
#pragma unroll
  for (int i = 0; i < 4; i++) {
    const int row = (wid * 4 + i) * 8 + lr8;         // 0..127
    const int grow = rbase + row;
    int tok = 0;
    if (grow < cnt) tok = slot_list[e * CAP + grow] >> 1;
    pa[i] = xb + (size_t)tok * D_DIM + kperm;
    pb[i] = w1t + ((size_t)e * H_DIM + n0 + row) * D_DIM + kperm;
    lo[i] = (wid * 4 + i) * 512;                      // wave-uniform LDS base (u16)
  }

  f32x4 acc[4][4];
#pragma unroll
  for (int i = 0; i < 4; i++)
#pragma unroll
    for (int j = 0; j < 4; j++) acc[i][j] = (f32x4){0.f, 0.f, 0.f, 0.f};

  auto stage = [&](int k0, int b) {
#pragma unroll
    for (int i = 0; i < 4; i++) gload16(pa[i] + k0, &At[b][lo[i]]);
#pragma unroll
    for (int i = 0; i < 4; i++) gload16(pb[i] + k0, &Bt[b][lo[i]]);
  };

  stage(0, 0);
  __syncthreads();
  int cur = 0;
  const int nt = D_DIM / 64;   // 8
  for (int t = 0; t < nt; ++t) {
    if (t + 1 < nt) stage((t + 1) * 64, cur ^ 1);
#pragma unroll
    for (int ks = 0; ks < 2; ks++) {
      bf16x8 afr[4], bfr[4];
#pragma unroll
      for (int f = 0; f < 4; f++) {
        afr[f] = *(const bf16x8*)(&At[cur][(wr * 64 + f * 16 + lrow) * 64 + ((ks * 4 + lk) ^ sx) * 8]);
        bfr[f] = *(const bf16x8*)(&Bt[cur][(wc * 64 + f * 16 + lrow) * 64 + ((ks * 4 + lk) ^ sx) * 8]);
      }
#pragma unroll
      for (int fr = 0; fr < 4; fr++)
#pragma unroll
        for (int fc = 0; fc < 4; fc++)
          acc[fr][fc] = __builtin_amdgcn_mfma_f32_16x16x32_bf16(afr[fr], bfr[fc], acc[fr][fc], 0, 0, 0);
    }
    __syncthreads();
    cur ^= 1;
  }

  float bias[4];
#pragma unroll
  for (int fc = 0; fc < 4; fc++) bias[fc] = b1[e * H_DIM + n0 + wc * 64 + fc * 16 + lrow];
#pragma unroll
  for (int fr = 0; fr < 4; fr++) {
#pragma unroll
    for (int reg = 0; reg < 4; reg++) {
      const int rloc = wr * 64 + fr * 16 + lk * 4 + reg;
      const int grow = rbase + rloc;
      if (grow < cnt) {
        const int slot = slot_list[e * CAP + grow];
        const float p  = prob_list[e * CAP + grow];
        u16* dst = hbuf + (size_t)slot * H_DIM + n0 + wc * 64 + lrow;
#pragma unroll
        for (int fc = 0; fc < 4; fc++) {
          float v = acc[fr][fc][reg] + bias[fc];
          dst[fc * 16] = f2bf(gelu_fast(v) * p);
        }
      }
    }
  }
}

// ---------------- grouped GEMM2: y_part = (h @ w2[kslice]) (+ p*b2 on s==0) ----------------
// tile 64x128, BK=64, split-K=2, dbuf 2-phase pipeline, T2 swizzle
// grid: (D/128=4, E*64, 2)
__global__ __launch_bounds__(256) void gemm2_kernel(const u16* __restrict__ hbuf,  // [2T][H]
                                                    const u16* __restrict__ w2t,   // [E][D][H]
                                                    const float* __restrict__ b2,  // [E][D]
                                                    const int* __restrict__ slot_list,
                                                    const float* __restrict__ prob_list,
                                                    const int* __restrict__ counts,
                                                    float* __restrict__ ypart) {   // [2][2T][D]
  const int e  = blockIdx.y >> 6;
  const int rt = blockIdx.y & 63;
  const int s  = blockIdx.z;
  const int cnt = counts[e];
  const int rbase = rt * 64;
  if (rbase >= cnt) return;
  const int n0 = blockIdx.x * 128;
  const int kb = s * (H_DIM / 2);

  __shared__ __align__(16) u16 At[2][64 * 64];
  __shared__ __align__(16) u16 Bt[2][128 * 64];

  const int tid = threadIdx.x, lane = tid & 63, wid = tid >> 6;
  const int wr = wid >> 1, wc = wid & 1;
  const int lr8 = lane >> 3;
  const int sx = lane & 7;
  const int kperm = (sx ^ lr8) * 8;
  const int lrow = lane & 15, lk = lane >> 4;

  const u16* pa[2]; int loa[2];
#pragma unroll
  for (int i = 0; i < 2; i++) {
    const int row = (wid * 2 + i) * 8 + lr8;          // 0..63
    const int grow = rbase + row;
    int slot = 0;
    if (grow < cnt) slot = slot_list[e * CAP + grow];
    pa[i] = hbuf + (size_t)slot * H_DIM + kb + kperm;
    loa[i] = (wid * 2 + i) * 512;
  }
  const u16* pb[4]; int lob[4];
#pragma unroll
  for (int i = 0; i < 4; i++) {
    const int row = (wid * 4 + i) * 8 + lr8;          // 0..127
    pb[i] = w2t + ((size_t)e * D_DIM + n0 + row) * H_DIM + kb + kperm;
    lob[i] = (wid * 4 + i) * 512;
  }

  f32x4 acc[2][4];
#pragma unroll
  for (int i = 0; i < 2; i++)
#pragma unroll
    for (int j = 0; j < 4; j++) acc[i][j] = (f32x4){0.f, 0.f, 0.f, 0.f};

  auto stage = [&](int k0, int b) {
#pragma unroll
    for (int i = 0; i < 2; i++) gload16(pa[i] + k0, &At[b][loa[i]]);
#pragma unroll
    for (int i = 0; i < 4; i++) gload16(pb[i] + k0, &Bt[b][lob[i]]);
  };

  stage(0, 0);
  __syncthreads();
  int cur = 0;
  const int nt = (H_DIM / 2) / 64;   // 16
  for (int t = 0; t < nt; ++t) {
    if (t + 1 < nt) stage((t + 1) * 64, cur ^ 1);
#pragma unroll
    for (int ks = 0; ks < 2; ks++) {
      bf16x8 afr[2], bfr[4];
#pragma unroll
      for (int f = 0; f < 2; f++)
        afr[f] = *(const bf16x8*)(&At[cur][(wr * 32 + f * 16 + lrow) * 64 + ((ks * 4 + lk) ^ sx) * 8]);
#pragma unroll
      for (int f = 0; f < 4; f++)
        bfr[f] = *(const bf16x8*)(&Bt[cur][(wc * 64 + f * 16 + lrow) * 64 + ((ks * 4 + lk) ^ sx) * 8]);
#pragma unroll
      for (int fr = 0; fr < 2; fr++)
#pragma unroll
        for (int fc = 0; fc < 4; fc++)
          acc[fr][fc] = __builtin_amdgcn_mfma_f32_16x16x32_bf16(afr[fr], bfr[fc], acc[fr][fc], 0, 0, 0);
    }
    __syncthreads();
    cur ^= 1;
  }

#pragma unroll
  for (int fr = 0; fr < 2; fr++) {
#pragma unroll
    for (int reg = 0; reg < 4; reg++) {
      const int rloc = wr * 32 + fr * 16 + lk * 4 + reg;
      const int grow = rbase + rloc;
      if (grow < cnt) {
        const int slot = slot_list[e * CAP + grow];
        const float p  = prob_list[e * CAP + grow];
        float* dst = ypart + ((size_t)s * NSLOT + slot) * D_DIM + n0 + wc * 64 + lrow;
#pragma unroll
        for (int fc = 0; fc < 4; fc++) {
          float v = acc[fr][fc][reg];
          if (s == 0) v += p * b2[e * D_DIM + n0 + wc * 64 + fc * 16 + lrow];
          dst[fc * 16] = v;
        }
      }
    }
  }
}

// ---------------- combine: out[t] = sum over 2 slots x 2 K-splits ----------------
__global__ __launch_bounds__(256) void combine_kernel(const float* __restrict__ yp,
                                                      float* __restrict__ out) {
  int i = blockIdx.x * 256 + threadIdx.x;   // over T*D/4
  int t = i >> 7;          // D/4 = 128
  int dq = i & 127;
  float4 a = ((const float4*)(yp + (size_t)(t * 2) * D_DIM))[dq];
  float4 b = ((const float4*)(yp + (size_t)(t * 2 + 1) * D_DIM))[dq];
  float4 c = ((const float4*)(yp + ((size_t)NSLOT + t * 2) * D_DIM))[dq];
  float4 d = ((const float4*)(yp + ((size_t)NSLOT + t * 2 + 1) * D_DIM))[dq];
  float4 r;
  r.x = a.x + b.x + c.x + d.x;
  r.y = a.y + b.y + c.y + d.y;
  r.z = a.z + b.z + c.z + d.z;
  r.w = a.w + b.w + c.w + d.w;
  ((float4*)(out + (size_t)t * D_DIM))[dq] = r;
}

extern "C" void kernel_launch(void* const* d_in, const int* in_sizes, int n_in,
                              void* d_out, int out_size, void* d_ws, size_t ws_size,
                              hipStream_t stream) {
  const float* x  = (const float*)d_in[0];
  const float* w1 = (const float*)d_in[1];
  const float* w2 = (const float*)d_in[2];
  const float* b1 = (const float*)d_in[3];
  const float* b2 = (const float*)d_in[4];
  const float* rw = (const float*)d_in[5];
  const float* rb = (const float*)d_in[6];
  float* out = (float*)d_out;

  char* ws = (char*)d_ws;
  size_t off = 0;
  auto alloc = [&](size_t bytes) -> void* {
    void* p = ws + off;
    off = (off + bytes + 255) & ~(size_t)255;
    return p;
  };
  int*   counts    = (int*)alloc(E_NUM * 4);
  int*   slot_list = (int*)alloc((size_t)E_NUM * CAP * 4);
  float* prob_list = (float*)alloc((size_t)E_NUM * CAP * 4);
  int*   topk_idx  = (int*)alloc((size_t)T_TOKENS * 2 * 4);
  float* topk_p    = (float*)alloc((size_t)T_TOKENS * 2 * 4);
  u16*   xb        = (u16*)alloc((size_t)T_TOKENS * D_DIM * 2);
  u16*   w1t       = (u16*)alloc((size_t)E_NUM * H_DIM * D_DIM * 2);
  u16*   w2t       = (u16*)alloc((size_t)E_NUM * H_DIM * D_DIM * 2);
  u16*   hbuf      = (u16*)alloc((size_t)NSLOT * H_DIM * 2);
  float* ypart     = (float*)alloc((size_t)2 * NSLOT * D_DIM * 4);

  transpose_bf16_kernel<<<dim3(H_DIM / 32, D_DIM / 32, E_NUM), dim3(32, 8), 0, stream>>>(w1, w1t, D_DIM, H_DIM);
  transpose_bf16_kernel<<<dim3(D_DIM / 32, H_DIM / 32, E_NUM), dim3(32, 8), 0, stream>>>(w2, w2t, H_DIM, D_DIM);
  router_kernel<<<T_TOKENS / 4, 256, 0, stream>>>(x, rw, rb, topk_idx, topk_p, xb);
  compact_kernel<<<E_NUM, 256, 0, stream>>>(topk_idx, topk_p, slot_list, prob_list, counts);
  gemm1_kernel<<<dim3(H_DIM / 128, E_NUM * 32), 256, 0, stream>>>(xb, w1t, b1, slot_list, prob_list, counts, hbuf);
  gemm2_kernel<<<dim3(D_DIM / 128, E_NUM * 64, 2), 256, 0, stream>>>(hbuf, w2t, b2, slot_list, prob_list, counts, ypart);
  combine_kernel<<<(T_TOKENS * D_DIM / 4) / 256, 256, 0, stream>>>(ypart, out);
}

// Round 4
// 136.301 us; speedup vs baseline: 2.6111x; 1.0656x over previous
//
#include <hip/hip_runtime.h>
#include <math.h>

typedef unsigned short u16;
typedef __bf16 bf16x8 __attribute__((ext_vector_type(8)));
typedef float f32x4 __attribute__((ext_vector_type(4)));

#define T_TOKENS 4096   // B*S
#define D_DIM    512
#define H_DIM    2048
#define E_NUM    8
#define CAP      4096   // per-expert worst-case capacity
#define NSLOT    (T_TOKENS * 2)

__device__ __forceinline__ u16 f2bf(float f) {
  unsigned int u = __builtin_bit_cast(unsigned int, f);
  u = (u + 0x7fffu + ((u >> 16) & 1u)) >> 16;   // RNE
  return (u16)u;
}

__device__ __forceinline__ void gload16(const void* g, void* l) {
  __builtin_amdgcn_global_load_lds(
      (__attribute__((address_space(1))) void*)(g),
      (__attribute__((address_space(3))) void*)(l), 16, 0, 0);
}

// gelu(v) ~= v * sigmoid(v*(1.59576912 + 0.071354817*v^2))  (tanh-form, |err|<~3e-4)
__device__ __forceinline__ float gelu_fast(float v) {
  float u = v * __fmaf_rn(0.071354817f, v * v, 1.59576912f);
  return v / (1.0f + __expf(-u));
}

// ---------------- f32 [E][R][C] -> bf16 [E][C][R] transpose (64x64 tiles) ----------------
__global__ __launch_bounds__(256) void transpose_bf16_kernel(const float* __restrict__ in,
                                                             u16* __restrict__ out,
                                                             int R, int C) {
  __shared__ float tile[64][67];
  const int e = blockIdx.z;
  const int c0 = blockIdx.x * 64, r0 = blockIdx.y * 64;
  const float* src = in + (size_t)e * R * C;
  u16* dst = out + (size_t)e * R * C;
  const int tid = threadIdx.x;
  // load: row = tid/4 (64 rows), col chunk = tid%4 (16 f32 each)
  {
    const int row = tid >> 2, cc = (tid & 3) * 16;
    const float* s = src + (size_t)(r0 + row) * C + c0 + cc;
#pragma unroll
    for (int j = 0; j < 4; j++) {
      float4 v = *(const float4*)(s + 4 * j);
      *(float4*)(&tile[row][cc + 4 * j]) = v;
    }
  }
  __syncthreads();
  // store: c = tid/4 (64 cols), r chunk = tid%4 (16 rows each)
  {
    const int c = tid >> 2, rc = (tid & 3) * 16;
    ushort8_t: ;
    u16 buf[16];
#pragma unroll
    for (int j = 0; j < 16; j++) buf[j] = f2bf(tile[rc + j][c]);
    u16* d = dst + (size_t)(c0 + c) * R + r0 + rc;
    *(uint4*)(d) = *(uint4*)(&buf[0]);
    *(uint4*)(d + 8) = *(uint4*)(&buf[8]);
  }
}

// ---------------- router + x->bf16: logits, top-2, softmax ----------------
__global__ __launch_bounds__(256) void router_kernel(const float* __restrict__ x,
                                                     const float* __restrict__ rw,
                                                     const float* __restrict__ rb,
                                                     int* __restrict__ topk_idx,
                                                     float* __restrict__ topk_p,
                                                     u16* __restrict__ xb) {
  const int lane = threadIdx.x & 63;
  const int t = blockIdx.x * 4 + (threadIdx.x >> 6);
  const float* xr = x + (size_t)t * D_DIM + lane * 8;
  float xv[8];
  *(float4*)(&xv[0]) = *(const float4*)(xr);
  *(float4*)(&xv[4]) = *(const float4*)(xr + 4);
  ushort4 o0, o1;
  o0.x = f2bf(xv[0]); o0.y = f2bf(xv[1]); o0.z = f2bf(xv[2]); o0.w = f2bf(xv[3]);
  o1.x = f2bf(xv[4]); o1.y = f2bf(xv[5]); o1.z = f2bf(xv[6]); o1.w = f2bf(xv[7]);
  ushort4* xo = (ushort4*)(xb + (size_t)t * D_DIM + lane * 8);
  xo[0] = o0; xo[1] = o1;

  float acc[8] = {0.f,0.f,0.f,0.f,0.f,0.f,0.f,0.f};
#pragma unroll
  for (int j = 0; j < 8; j++) {
    const float4* w = (const float4*)(rw + (size_t)(lane * 8 + j) * E_NUM);
    float4 w0 = w[0], w1 = w[1];
    acc[0] += xv[j] * w0.x; acc[1] += xv[j] * w0.y;
    acc[2] += xv[j] * w0.z; acc[3] += xv[j] * w0.w;
    acc[4] += xv[j] * w1.x; acc[5] += xv[j] * w1.y;
    acc[6] += xv[j] * w1.z; acc[7] += xv[j] * w1.w;
  }
#pragma unroll
  for (int off = 32; off > 0; off >>= 1) {
#pragma unroll
    for (int e = 0; e < 8; e++) acc[e] += __shfl_down(acc[e], off);
  }
  if (lane == 0) {
    float l[8];
#pragma unroll
    for (int e = 0; e < 8; e++) l[e] = acc[e] + rb[e];
    int i0 = 0; float v0 = l[0];
#pragma unroll
    for (int e = 1; e < 8; e++) if (l[e] > v0) { v0 = l[e]; i0 = e; }
    int i1 = -1; float v1 = -3.4e38f;
#pragma unroll
    for (int e = 0; e < 8; e++) if (e != i0 && l[e] > v1) { v1 = l[e]; i1 = e; }
    float p1 = expf(v1 - v0);
    float s = 1.0f + p1;
    topk_idx[t * 2] = i0; topk_idx[t * 2 + 1] = i1;
    topk_p[t * 2] = 1.0f / s; topk_p[t * 2 + 1] = p1 / s;
  }
}

// ---------------- deterministic per-expert compaction (ballot scan) ----------------
__global__ __launch_bounds__(256) void compact_kernel(const int* __restrict__ topk_idx,
                                                      const float* __restrict__ topk_p,
                                                      int* __restrict__ slot_list,
                                                      float* __restrict__ prob_list,
                                                      int* __restrict__ counts) {
  const int e = blockIdx.x;
  const int tid = threadIdx.x, lane = tid & 63, w = tid >> 6;
  __shared__ int wsum[4];
  __shared__ int sbase;
  if (tid == 0) sbase = 0;
  __syncthreads();
  for (int c0 = 0; c0 < T_TOKENS; c0 += 256) {
    const int t = c0 + tid;
    const int i0 = topk_idx[t * 2], i1 = topk_idx[t * 2 + 1];
    int flag = 0, slot = 0; float p = 0.f;
    if (i0 == e)      { flag = 1; slot = t * 2;     p = topk_p[t * 2]; }
    else if (i1 == e) { flag = 1; slot = t * 2 + 1; p = topk_p[t * 2 + 1]; }
    unsigned long long m = __ballot(flag);
    if (lane == 0) wsum[w] = (int)__popcll(m);
    const int wpre = (int)__popcll(m & ((1ull << lane) - 1ull));
    __syncthreads();
    int base = sbase;
#pragma unroll
    for (int j = 0; j < 4; j++) if (j < w) base += wsum[j];
    const int tot = wsum[0] + wsum[1] + wsum[2] + wsum[3];
    if (flag) { slot_list[e * CAP + base + wpre] = slot; prob_list[e * CAP + base + wpre] = p; }
    __syncthreads();
    if (tid == 0) sbase += tot;
  }
  __syncthreads();
  if (tid == 0) counts[e] = sbase;
}

// ---------------- grouped GEMM1: h = gelu(x @ w1 + b1) * p  (bf16, by slot) ----------------
// tile 128x128, BK=64, counted-vmcnt pipeline (T3/T4-lite), T2 swizzle
// grid: (H/128=16, E*32)
__global__ __launch_bounds__(256) void gemm1_kernel(const u16* __restrict__ xb,
                                                    const u16* __restrict__ w1t,   // [E][H][D]
                                                    const float* __restrict__ b1,  // [E][H]
                                                    const int* __restrict__ slot_list,
                                                    const float* __restrict__ prob_list,
                                                    const int* __restrict__ counts,
                                                    u16* __restrict__ hbuf) {      // [2T][H]
  const int e  = blockIdx.y >> 5;
  const int rt = blockIdx.y & 31;
  const int cnt = counts[e];
  const int rbase = rt * 128;
  if (rbase >= cnt) return;
  const int n0 = blockIdx.x * 128;

  __shared__ __align__(16) u16 At[2][128 * 64];
  __shared__ __align__(16) u16 Bt[2][128 * 64];

  const int tid = threadIdx.x, lane = tid & 63, wid = tid >> 6;
  const int wr = wid >> 1, wc = wid & 1;
  const int lr8 = lane >> 3;
  const int sx = lane & 7;                     // swizzle key (read side)
  const int kperm = (sx ^ lr8) * 8;            // pre-permuted source chunk (stage side)
  const int lrow = lane & 15, lk = lane >> 4;

  const u16* pa[4]; const u16* pb[4]; int lo[4];
#pragma unroll
  for (int i = 0; i < 4; i++) {
    const int row = (wid * 4 + i) * 8 + lr8;         // 0..127
    const int grow = rbase + row;
    int tok = 0;
    if (grow < cnt) tok = slot_list[e * CAP + grow] >> 1;
    pa[i] = xb + (size_t)tok * D_DIM + kperm;
    pb[i] = w1t + ((size_t)e * H_DIM + n0 + row) * D_DIM + kperm;
    lo[i] = (wid * 4 + i) * 512;                      // wave-uniform LDS base (u16)
  }

  f32x4 acc[4][4];
#pragma unroll
  for (int i = 0; i < 4; i++)
#pragma unroll
    for (int j = 0; j < 4; j++) acc[i][j] = (f32x4){0.f, 0.f, 0.f, 0.f};

  auto stage = [&](int k0, int b) {   // 8 gload_lds per wave
#pragma unroll
    for (int i = 0; i < 4; i++) gload16(pa[i] + k0, &At[b][lo[i]]);
#pragma unroll
    for (int i = 0; i < 4; i++) gload16(pb[i] + k0, &Bt[b][lo[i]]);
  };

  stage(0, 0);
  stage(64, 1);
  const int nt = D_DIM / 64;   // 8
#pragma unroll
  for (int t = 0; t < nt; ++t) {
    const int cur = t & 1;
    // wait for stage(t) only: stage(t+1)'s 8 loads may stay in flight
    if (t < nt - 1) { asm volatile("s_waitcnt vmcnt(8)" ::: "memory"); }
    else            { asm volatile("s_waitcnt vmcnt(0)" ::: "memory"); }
    __builtin_amdgcn_sched_barrier(0);
    __builtin_amdgcn_s_barrier();            // buf[cur] fully written, all waves
    bf16x8 afr[4][2], bfr[4][2];
#pragma unroll
    for (int ks = 0; ks < 2; ks++)
#pragma unroll
      for (int f = 0; f < 4; f++) {
        afr[f][ks] = *(const bf16x8*)(&At[cur][(wr * 64 + f * 16 + lrow) * 64 + ((ks * 4 + lk) ^ sx) * 8]);
        bfr[f][ks] = *(const bf16x8*)(&Bt[cur][(wc * 64 + f * 16 + lrow) * 64 + ((ks * 4 + lk) ^ sx) * 8]);
      }
    asm volatile("s_waitcnt lgkmcnt(0)" ::: "memory");
    __builtin_amdgcn_sched_barrier(0);
    __builtin_amdgcn_s_barrier();            // all waves done reading buf[cur]
    if (t + 2 < nt) stage((t + 2) * 64, cur);  // overwrite just-freed buffer
    __builtin_amdgcn_sched_barrier(0);
    __builtin_amdgcn_s_setprio(1);
#pragma unroll
    for (int ks = 0; ks < 2; ks++)
#pragma unroll
      for (int fr = 0; fr < 4; fr++)
#pragma unroll
        for (int fc = 0; fc < 4; fc++)
          acc[fr][fc] = __builtin_amdgcn_mfma_f32_16x16x32_bf16(afr[fr][ks], bfr[fc][ks], acc[fr][fc], 0, 0, 0);
    __builtin_amdgcn_s_setprio(0);
  }

  float bias[4];
#pragma unroll
  for (int fc = 0; fc < 4; fc++) bias[fc] = b1[e * H_DIM + n0 + wc * 64 + fc * 16 + lrow];
#pragma unroll
  for (int fr = 0; fr < 4; fr++) {
#pragma unroll
    for (int reg = 0; reg < 4; reg++) {
      const int rloc = wr * 64 + fr * 16 + lk * 4 + reg;
      const int grow = rbase + rloc;
      if (grow < cnt) {
        const int slot = slot_list[e * CAP + grow];
        const float p  = prob_list[e * CAP + grow];
        u16* dst = hbuf + (size_t)slot * H_DIM + n0 + wc * 64 + lrow;
#pragma unroll
        for (int fc = 0; fc < 4; fc++) {
          float v = acc[fr][fc][reg] + bias[fc];
          dst[fc * 16] = f2bf(gelu_fast(v) * p);
        }
      }
    }
  }
}

// ---------------- grouped GEMM2: y_part = (h @ w2[kslice]) (+ p*b2 on s==0) ----------------
// tile 64x128, BK=64, split-K=2, counted-vmcnt pipeline, T2 swizzle
// grid: (D/128=4, E*64, 2)
__global__ __launch_bounds__(256) void gemm2_kernel(const u16* __restrict__ hbuf,  // [2T][H]
                                                    const u16* __restrict__ w2t,   // [E][D][H]
                                                    const float* __restrict__ b2,  // [E][D]
                                                    const int* __restrict__ slot_list,
                                                    const float* __restrict__ prob_list,
                                                    const int* __restrict__ counts,
                                                    float* __restrict__ ypart) {   // [2][2T][D]
  const int e  = blockIdx.y >> 6;
  const int rt = blockIdx.y & 63;
  const int s  = blockIdx.z;
  const int cnt = counts[e];
  const int rbase = rt * 64;
  if (rbase >= cnt) return;
  const int n0 = blockIdx.x * 128;
  const int kb = s * (H_DIM / 2);

  __shared__ __align__(16) u16 At[2][64 * 64];
  __shared__ __align__(16) u16 Bt[2][128 * 64];

  const int tid = threadIdx.x, lane = tid & 63, wid = tid >> 6;
  const int wr = wid >> 1, wc = wid & 1;
  const int lr8 = lane >> 3;
  const int sx = lane & 7;
  const int kperm = (sx ^ lr8) * 8;
  const int lrow = lane & 15, lk = lane >> 4;

  const u16* pa[2]; int loa[2];
#pragma unroll
  for (int i = 0; i < 2; i++) {
    const int row = (wid * 2 + i) * 8 + lr8;          // 0..63
    const int grow = rbase + row;
    int slot = 0;
    if (grow < cnt) slot = slot_list[e * CAP + grow];
    pa[i] = hbuf + (size_t)slot * H_DIM + kb + kperm;
    loa[i] = (wid * 2 + i) * 512;
  }
  const u16* pb[4]; int lob[4];
#pragma unroll
  for (int i = 0; i < 4; i++) {
    const int row = (wid * 4 + i) * 8 + lr8;          // 0..127
    pb[i] = w2t + ((size_t)e * D_DIM + n0 + row) * H_DIM + kb + kperm;
    lob[i] = (wid * 4 + i) * 512;
  }

  f32x4 acc[2][4];
#pragma unroll
  for (int i = 0; i < 2; i++)
#pragma unroll
    for (int j = 0; j < 4; j++) acc[i][j] = (f32x4){0.f, 0.f, 0.f, 0.f};

  auto stage = [&](int k0, int b) {   // 6 gload_lds per wave
#pragma unroll
    for (int i = 0; i < 2; i++) gload16(pa[i] + k0, &At[b][loa[i]]);
#pragma unroll
    for (int i = 0; i < 4; i++) gload16(pb[i] + k0, &Bt[b][lob[i]]);
  };

  stage(0, 0);
  stage(64, 1);
  const int nt = (H_DIM / 2) / 64;   // 16
#pragma unroll
  for (int t = 0; t < nt; ++t) {
    const int cur = t & 1;
    if (t < nt - 1) { asm volatile("s_waitcnt vmcnt(6)" ::: "memory"); }
    else            { asm volatile("s_waitcnt vmcnt(0)" ::: "memory"); }
    __builtin_amdgcn_sched_barrier(0);
    __builtin_amdgcn_s_barrier();
    bf16x8 afr[2][2], bfr[4][2];
#pragma unroll
    for (int ks = 0; ks < 2; ks++) {
#pragma unroll
      for (int f = 0; f < 2; f++)
        afr[f][ks] = *(const bf16x8*)(&At[cur][(wr * 32 + f * 16 + lrow) * 64 + ((ks * 4 + lk) ^ sx) * 8]);
#pragma unroll
      for (int f = 0; f < 4; f++)
        bfr[f][ks] = *(const bf16x8*)(&Bt[cur][(wc * 64 + f * 16 + lrow) * 64 + ((ks * 4 + lk) ^ sx) * 8]);
    }
    asm volatile("s_waitcnt lgkmcnt(0)" ::: "memory");
    __builtin_amdgcn_sched_barrier(0);
    __builtin_amdgcn_s_barrier();
    if (t + 2 < nt) stage((t + 2) * 64, cur);
    __builtin_amdgcn_sched_barrier(0);
    __builtin_amdgcn_s_setprio(1);
#pragma unroll
    for (int ks = 0; ks < 2; ks++)
#pragma unroll
      for (int fr = 0; fr < 2; fr++)
#pragma unroll
        for (int fc = 0; fc < 4; fc++)
          acc[fr][fc] = __builtin_amdgcn_mfma_f32_16x16x32_bf16(afr[fr][ks], bfr[fc][ks], acc[fr][fc], 0, 0, 0);
    __builtin_amdgcn_s_setprio(0);
  }

#pragma unroll
  for (int fr = 0; fr < 2; fr++) {
#pragma unroll
    for (int reg = 0; reg < 4; reg++) {
      const int rloc = wr * 32 + fr * 16 + lk * 4 + reg;
      const int grow = rbase + rloc;
      if (grow < cnt) {
        const int slot = slot_list[e * CAP + grow];
        const float p  = prob_list[e * CAP + grow];
        float* dst = ypart + ((size_t)s * NSLOT + slot) * D_DIM + n0 + wc * 64 + lrow;
#pragma unroll
        for (int fc = 0; fc < 4; fc++) {
          float v = acc[fr][fc][reg];
          if (s == 0) v += p * b2[e * D_DIM + n0 + wc * 64 + fc * 16 + lrow];
          dst[fc * 16] = v;
        }
      }
    }
  }
}

// ---------------- combine: out[t] = sum over 2 slots x 2 K-splits ----------------
__global__ __launch_bounds__(256) void combine_kernel(const float* __restrict__ yp,
                                                      float* __restrict__ out) {
  int i = blockIdx.x * 256 + threadIdx.x;   // over T*D/4
  int t = i >> 7;          // D/4 = 128
  int dq = i & 127;
  float4 a = ((const float4*)(yp + (size_t)(t * 2) * D_DIM))[dq];
  float4 b = ((const float4*)(yp + (size_t)(t * 2 + 1) * D_DIM))[dq];
  float4 c = ((const float4*)(yp + ((size_t)NSLOT + t * 2) * D_DIM))[dq];
  float4 d = ((const float4*)(yp + ((size_t)NSLOT + t * 2 + 1) * D_DIM))[dq];
  float4 r;
  r.x = a.x + b.x + c.x + d.x;
  r.y = a.y + b.y + c.y + d.y;
  r.z = a.z + b.z + c.z + d.z;
  r.w = a.w + b.w + c.w + d.w;
  ((float4*)(out + (size_t)t * D_DIM))[dq] = r;
}

extern "C" void kernel_launch(void* const* d_in, const int* in_sizes, int n_in,
                              void* d_out, int out_size, void* d_ws, size_t ws_size,
                              hipStream_t stream) {
  const float* x  = (const float*)d_in[0];
  const float* w1 = (const float*)d_in[1];
  const float* w2 = (const float*)d_in[2];
  const float* b1 = (const float*)d_in[3];
  const float* b2 = (const float*)d_in[4];
  const float* rw = (const float*)d_in[5];
  const float* rb = (const float*)d_in[6];
  float* out = (float*)d_out;

  char* ws = (char*)d_ws;
  size_t off = 0;
  auto alloc = [&](size_t bytes) -> void* {
    void* p = ws + off;
    off = (off + bytes + 255) & ~(size_t)255;
    return p;
  };
  int*   counts    = (int*)alloc(E_NUM * 4);
  int*   slot_list = (int*)alloc((size_t)E_NUM * CAP * 4);
  float* prob_list = (float*)alloc((size_t)E_NUM * CAP * 4);
  int*   topk_idx  = (int*)alloc((size_t)T_TOKENS * 2 * 4);
  float* topk_p    = (float*)alloc((size_t)T_TOKENS * 2 * 4);
  u16*   xb        = (u16*)alloc((size_t)T_TOKENS * D_DIM * 2);
  u16*   w1t       = (u16*)alloc((size_t)E_NUM * H_DIM * D_DIM * 2);
  u16*   w2t       = (u16*)alloc((size_t)E_NUM * H_DIM * D_DIM * 2);
  u16*   hbuf      = (u16*)alloc((size_t)NSLOT * H_DIM * 2);
  float* ypart     = (float*)alloc((size_t)2 * NSLOT * D_DIM * 4);

  transpose_bf16_kernel<<<dim3(H_DIM / 64, D_DIM / 64, E_NUM), 256, 0, stream>>>(w1, w1t, D_DIM, H_DIM);
  transpose_bf16_kernel<<<dim3(D_DIM / 64, H_DIM / 64, E_NUM), 256, 0, stream>>>(w2, w2t, H_DIM, D_DIM);
  router_kernel<<<T_TOKENS / 4, 256, 0, stream>>>(x, rw, rb, topk_idx, topk_p, xb);
  compact_kernel<<<E_NUM, 256, 0, stream>>>(topk_idx, topk_p, slot_list, prob_list, counts);
  gemm1_kernel<<<dim3(H_DIM / 128, E_NUM * 32), 256, 0, stream>>>(xb, w1t, b1, slot_list, prob_list, counts, hbuf);
  gemm2_kernel<<<dim3(D_DIM / 128, E_NUM * 64, 2), 256, 0, stream>>>(hbuf, w2t, b2, slot_list, prob_list, counts, ypart);
  combine_kernel<<<(T_TOKENS * D_DIM / 4) / 256, 256, 0, stream>>>(ypart, out);
}

// Round 5
// 129.017 us; speedup vs baseline: 2.7585x; 1.0565x over previous
//
#include <hip/hip_runtime.h>
#include <math.h>

typedef unsigned short u16;
typedef __bf16 bf16x8 __attribute__((ext_vector_type(8)));
typedef float f32x4 __attribute__((ext_vector_type(4)));

#define T_TOKENS 4096   // B*S
#define D_DIM    512
#define H_DIM    2048
#define E_NUM    8
#define CAP      4096   // per-expert worst-case capacity
#define NSLOT    (T_TOKENS * 2)

__device__ __forceinline__ u16 f2bf(float f) {
  unsigned int u = __builtin_bit_cast(unsigned int, f);
  u = (u + 0x7fffu + ((u >> 16) & 1u)) >> 16;   // RNE
  return (u16)u;
}

__device__ __forceinline__ void gload16(const void* g, void* l) {
  __builtin_amdgcn_global_load_lds(
      (__attribute__((address_space(1))) void*)(g),
      (__attribute__((address_space(3))) void*)(l), 16, 0, 0);
}

// gelu(v) ~= v * sigmoid(v*(1.59576912 + 0.071354817*v^2)); rcp instead of slow f32 div
__device__ __forceinline__ float gelu_fast(float v) {
  float u = v * __fmaf_rn(0.071354817f, v * v, 1.59576912f);
  float e = __expf(-u);
  return v * __builtin_amdgcn_rcpf(1.0f + e);
}

// ---------------- both weights: f32 [E][R][C] -> bf16 [E][C][R], one launch ----------------
// w1: R=D,C=H (32x8 tiles/e); w2: R=H,C=D (8x32 tiles/e); 256 tiles/e each; grid 4096
__global__ __launch_bounds__(256) void transpose_both_kernel(const float* __restrict__ w1,
                                                             const float* __restrict__ w2,
                                                             u16* __restrict__ w1t,
                                                             u16* __restrict__ w2t) {
  __shared__ float tile[64][67];
  int bid = blockIdx.x;
  const float* in; u16* out; int R, C;
  if (bid < 2048) { in = w1; out = w1t; R = D_DIM; C = H_DIM; }
  else            { bid -= 2048; in = w2; out = w2t; R = H_DIM; C = D_DIM; }
  const int e = bid >> 8;
  const int t = bid & 255;
  const int nCx = C >> 6;
  const int c0 = (t % nCx) * 64, r0 = (t / nCx) * 64;
  const float* src = in + (size_t)e * D_DIM * H_DIM;
  u16* dst = out + (size_t)e * D_DIM * H_DIM;
  const int tid = threadIdx.x;
  {
    const int row = tid >> 2, cc = (tid & 3) * 16;
    const float* s = src + (size_t)(r0 + row) * C + c0 + cc;
#pragma unroll
    for (int j = 0; j < 4; j++)
      *(float4*)(&tile[row][cc + 4 * j]) = *(const float4*)(s + 4 * j);
  }
  __syncthreads();
  {
    const int c = tid >> 2, rc = (tid & 3) * 16;
    u16 buf[16];
#pragma unroll
    for (int j = 0; j < 16; j++) buf[j] = f2bf(tile[rc + j][c]);
    u16* d = dst + (size_t)(c0 + c) * R + r0 + rc;
    *(uint4*)(d)     = *(uint4*)(&buf[0]);
    *(uint4*)(d + 8) = *(uint4*)(&buf[8]);
  }
}

// ---------------- router + x->bf16 + zero(out): logits, top-2, softmax ----------------
__global__ __launch_bounds__(256) void router_kernel(const float* __restrict__ x,
                                                     const float* __restrict__ rw,
                                                     const float* __restrict__ rb,
                                                     int* __restrict__ topk_idx,
                                                     float* __restrict__ topk_p,
                                                     u16* __restrict__ xb,
                                                     float* __restrict__ outz) {
  // zero the output buffer (gemm2 accumulates into it atomically)
  {
    float4 z = {0.f, 0.f, 0.f, 0.f};
    float4* o = (float4*)(outz + (size_t)blockIdx.x * 2048);
    o[threadIdx.x] = z;
    o[threadIdx.x + 256] = z;
  }
  const int lane = threadIdx.x & 63;
  const int t = blockIdx.x * 4 + (threadIdx.x >> 6);
  const float* xr = x + (size_t)t * D_DIM + lane * 8;
  float xv[8];
  *(float4*)(&xv[0]) = *(const float4*)(xr);
  *(float4*)(&xv[4]) = *(const float4*)(xr + 4);
  ushort4 o0, o1;
  o0.x = f2bf(xv[0]); o0.y = f2bf(xv[1]); o0.z = f2bf(xv[2]); o0.w = f2bf(xv[3]);
  o1.x = f2bf(xv[4]); o1.y = f2bf(xv[5]); o1.z = f2bf(xv[6]); o1.w = f2bf(xv[7]);
  ushort4* xo = (ushort4*)(xb + (size_t)t * D_DIM + lane * 8);
  xo[0] = o0; xo[1] = o1;

  float acc[8] = {0.f,0.f,0.f,0.f,0.f,0.f,0.f,0.f};
#pragma unroll
  for (int j = 0; j < 8; j++) {
    const float4* w = (const float4*)(rw + (size_t)(lane * 8 + j) * E_NUM);
    float4 w0 = w[0], w1 = w[1];
    acc[0] += xv[j] * w0.x; acc[1] += xv[j] * w0.y;
    acc[2] += xv[j] * w0.z; acc[3] += xv[j] * w0.w;
    acc[4] += xv[j] * w1.x; acc[5] += xv[j] * w1.y;
    acc[6] += xv[j] * w1.z; acc[7] += xv[j] * w1.w;
  }
#pragma unroll
  for (int off = 32; off > 0; off >>= 1) {
#pragma unroll
    for (int e = 0; e < 8; e++) acc[e] += __shfl_down(acc[e], off);
  }
  if (lane == 0) {
    float l[8];
#pragma unroll
    for (int e = 0; e < 8; e++) l[e] = acc[e] + rb[e];
    int i0 = 0; float v0 = l[0];
#pragma unroll
    for (int e = 1; e < 8; e++) if (l[e] > v0) { v0 = l[e]; i0 = e; }
    int i1 = -1; float v1 = -3.4e38f;
#pragma unroll
    for (int e = 0; e < 8; e++) if (e != i0 && l[e] > v1) { v1 = l[e]; i1 = e; }
    float p1 = expf(v1 - v0);
    float s = 1.0f + p1;
    topk_idx[t * 2] = i0; topk_idx[t * 2 + 1] = i1;
    topk_p[t * 2] = 1.0f / s; topk_p[t * 2 + 1] = p1 / s;
  }
}

// ---------------- deterministic per-expert compaction (ballot scan) ----------------
__global__ __launch_bounds__(256) void compact_kernel(const int* __restrict__ topk_idx,
                                                      const float* __restrict__ topk_p,
                                                      int* __restrict__ slot_list,
                                                      float* __restrict__ prob_list,
                                                      int* __restrict__ counts) {
  const int e = blockIdx.x;
  const int tid = threadIdx.x, lane = tid & 63, w = tid >> 6;
  __shared__ int wsum[4];
  __shared__ int sbase;
  if (tid == 0) sbase = 0;
  __syncthreads();
  for (int c0 = 0; c0 < T_TOKENS; c0 += 256) {
    const int t = c0 + tid;
    const int i0 = topk_idx[t * 2], i1 = topk_idx[t * 2 + 1];
    int flag = 0, slot = 0; float p = 0.f;
    if (i0 == e)      { flag = 1; slot = t * 2;     p = topk_p[t * 2]; }
    else if (i1 == e) { flag = 1; slot = t * 2 + 1; p = topk_p[t * 2 + 1]; }
    unsigned long long m = __ballot(flag);
    if (lane == 0) wsum[w] = (int)__popcll(m);
    const int wpre = (int)__popcll(m & ((1ull << lane) - 1ull));
    __syncthreads();
    int base = sbase;
#pragma unroll
    for (int j = 0; j < 4; j++) if (j < w) base += wsum[j];
    const int tot = wsum[0] + wsum[1] + wsum[2] + wsum[3];
    if (flag) { slot_list[e * CAP + base + wpre] = slot; prob_list[e * CAP + base + wpre] = p; }
    __syncthreads();
    if (tid == 0) sbase += tot;
  }
  __syncthreads();
  if (tid == 0) counts[e] = sbase;
}

// ---------------- grouped GEMM1: h = gelu(x @ w1 + b1) * p  (bf16, by slot) ----------------
// tile 128x128, BK=64, counted-vmcnt pipeline, T2 swizzle
// grid: (H/128=16, E*32)
__global__ __launch_bounds__(256, 2) void gemm1_kernel(const u16* __restrict__ xb,
                                                       const u16* __restrict__ w1t,   // [E][H][D]
                                                       const float* __restrict__ b1,  // [E][H]
                                                       const int* __restrict__ slot_list,
                                                       const float* __restrict__ prob_list,
                                                       const int* __restrict__ counts,
                                                       u16* __restrict__ hbuf) {      // [2T][H]
  const int e  = blockIdx.y >> 5;
  const int rt = blockIdx.y & 31;
  const int cnt = counts[e];
  const int rbase = rt * 128;
  if (rbase >= cnt) return;
  const int n0 = blockIdx.x * 128;

  __shared__ __align__(16) u16 At[2][128 * 64];
  __shared__ __align__(16) u16 Bt[2][128 * 64];

  const int tid = threadIdx.x, lane = tid & 63, wid = tid >> 6;
  const int wr = wid >> 1, wc = wid & 1;
  const int lr8 = lane >> 3;
  const int sx = lane & 7;                     // swizzle key (read side)
  const int kperm = (sx ^ lr8) * 8;            // pre-permuted source chunk (stage side)
  const int lrow = lane & 15, lk = lane >> 4;

  const u16* pa[4]; const u16* pb[4]; int lo[4];
#pragma unroll
  for (int i = 0; i < 4; i++) {
    const int row = (wid * 4 + i) * 8 + lr8;         // 0..127
    const int grow = rbase + row;
    int tok = 0;
    if (grow < cnt) tok = slot_list[e * CAP + grow] >> 1;
    pa[i] = xb + (size_t)tok * D_DIM + kperm;
    pb[i] = w1t + ((size_t)e * H_DIM + n0 + row) * D_DIM + kperm;
    lo[i] = (wid * 4 + i) * 512;                      // wave-uniform LDS base (u16)
  }

  f32x4 acc[4][4];
#pragma unroll
  for (int i = 0; i < 4; i++)
#pragma unroll
    for (int j = 0; j < 4; j++) acc[i][j] = (f32x4){0.f, 0.f, 0.f, 0.f};

  auto stage = [&](int k0, int b) {   // 8 gload_lds per thread
#pragma unroll
    for (int i = 0; i < 4; i++) gload16(pa[i] + k0, &At[b][lo[i]]);
#pragma unroll
    for (int i = 0; i < 4; i++) gload16(pb[i] + k0, &Bt[b][lo[i]]);
  };

  stage(0, 0);
  stage(64, 1);
  const int nt = D_DIM / 64;   // 8
#pragma unroll
  for (int t = 0; t < nt; ++t) {
    const int cur = t & 1;
    if (t < nt - 1) { asm volatile("s_waitcnt vmcnt(8)" ::: "memory"); }
    else            { asm volatile("s_waitcnt vmcnt(0)" ::: "memory"); }
    __builtin_amdgcn_sched_barrier(0);
    __builtin_amdgcn_s_barrier();            // buf[cur] fully written, all waves
    bf16x8 afr[4][2], bfr[4][2];
#pragma unroll
    for (int ks = 0; ks < 2; ks++)
#pragma unroll
      for (int f = 0; f < 4; f++) {
        afr[f][ks] = *(const bf16x8*)(&At[cur][(wr * 64 + f * 16 + lrow) * 64 + ((ks * 4 + lk) ^ sx) * 8]);
        bfr[f][ks] = *(const bf16x8*)(&Bt[cur][(wc * 64 + f * 16 + lrow) * 64 + ((ks * 4 + lk) ^ sx) * 8]);
      }
    asm volatile("s_waitcnt lgkmcnt(0)" ::: "memory");
    __builtin_amdgcn_sched_barrier(0);
    __builtin_amdgcn_s_barrier();            // all waves done reading buf[cur]
    if (t + 2 < nt) stage((t + 2) * 64, cur);
    __builtin_amdgcn_sched_barrier(0);
    __builtin_amdgcn_s_setprio(1);
#pragma unroll
    for (int ks = 0; ks < 2; ks++)
#pragma unroll
      for (int fr = 0; fr < 4; fr++)
#pragma unroll
        for (int fc = 0; fc < 4; fc++)
          acc[fr][fc] = __builtin_amdgcn_mfma_f32_16x16x32_bf16(afr[fr][ks], bfr[fc][ks], acc[fr][fc], 0, 0, 0);
    __builtin_amdgcn_s_setprio(0);
  }

  float bias[4];
#pragma unroll
  for (int fc = 0; fc < 4; fc++) bias[fc] = b1[e * H_DIM + n0 + wc * 64 + fc * 16 + lrow];
#pragma unroll
  for (int fr = 0; fr < 4; fr++) {
#pragma unroll
    for (int reg = 0; reg < 4; reg++) {
      const int rloc = wr * 64 + fr * 16 + lk * 4 + reg;
      const int grow = rbase + rloc;
      if (grow < cnt) {
        const int slot = slot_list[e * CAP + grow];
        const float p  = prob_list[e * CAP + grow];
        u16* dst = hbuf + (size_t)slot * H_DIM + n0 + wc * 64 + lrow;
#pragma unroll
        for (int fc = 0; fc < 4; fc++) {
          float v = acc[fr][fc][reg] + bias[fc];
          dst[fc * 16] = f2bf(gelu_fast(v) * p);
        }
      }
    }
  }
}

// ---------------- grouped GEMM2: out[t] += h @ w2 + p*b2  (atomic f32, 2 addends) ----------
// tile 64x128, BK=64, full K=2048, counted-vmcnt pipeline, T2 swizzle, 48KB LDS (3 blk/CU)
// grid: (D/128=4, E*64)
__global__ __launch_bounds__(256, 3) void gemm2_kernel(const u16* __restrict__ hbuf,  // [2T][H]
                                                       const u16* __restrict__ w2t,   // [E][D][H]
                                                       const float* __restrict__ b2,  // [E][D]
                                                       const int* __restrict__ slot_list,
                                                       const float* __restrict__ prob_list,
                                                       const int* __restrict__ counts,
                                                       float* __restrict__ out) {     // [T][D]
  const int e  = blockIdx.y >> 6;
  const int rt = blockIdx.y & 63;
  const int cnt = counts[e];
  const int rbase = rt * 64;
  if (rbase >= cnt) return;
  const int n0 = blockIdx.x * 128;

  __shared__ __align__(16) u16 At[2][64 * 64];
  __shared__ __align__(16) u16 Bt[2][128 * 64];

  const int tid = threadIdx.x, lane = tid & 63, wid = tid >> 6;
  const int wr = wid >> 1, wc = wid & 1;
  const int lr8 = lane >> 3;
  const int sx = lane & 7;
  const int kperm = (sx ^ lr8) * 8;
  const int lrow = lane & 15, lk = lane >> 4;

  const u16* pa[2]; int loa[2];
#pragma unroll
  for (int i = 0; i < 2; i++) {
    const int row = (wid * 2 + i) * 8 + lr8;          // 0..63
    const int grow = rbase + row;
    int slot = 0;
    if (grow < cnt) slot = slot_list[e * CAP + grow];
    pa[i] = hbuf + (size_t)slot * H_DIM + kperm;
    loa[i] = (wid * 2 + i) * 512;
  }
  const u16* pb[4]; int lob[4];
#pragma unroll
  for (int i = 0; i < 4; i++) {
    const int row = (wid * 4 + i) * 8 + lr8;          // 0..127
    pb[i] = w2t + ((size_t)e * D_DIM + n0 + row) * H_DIM + kperm;
    lob[i] = (wid * 4 + i) * 512;
  }

  f32x4 acc[2][4];
#pragma unroll
  for (int i = 0; i < 2; i++)
#pragma unroll
    for (int j = 0; j < 4; j++) acc[i][j] = (f32x4){0.f, 0.f, 0.f, 0.f};

  auto stage = [&](int k0, int b) {   // 6 gload_lds per thread
#pragma unroll
    for (int i = 0; i < 2; i++) gload16(pa[i] + k0, &At[b][loa[i]]);
#pragma unroll
    for (int i = 0; i < 4; i++) gload16(pb[i] + k0, &Bt[b][lob[i]]);
  };

  stage(0, 0);
  stage(64, 1);
  const int nt = H_DIM / 64;   // 32
#pragma unroll 2
  for (int t = 0; t < nt; ++t) {
    const int cur = t & 1;
    if (t < nt - 1) { asm volatile("s_waitcnt vmcnt(6)" ::: "memory"); }
    else            { asm volatile("s_waitcnt vmcnt(0)" ::: "memory"); }
    __builtin_amdgcn_sched_barrier(0);
    __builtin_amdgcn_s_barrier();
    bf16x8 afr[2][2], bfr[4][2];
#pragma unroll
    for (int ks = 0; ks < 2; ks++) {
#pragma unroll
      for (int f = 0; f < 2; f++)
        afr[f][ks] = *(const bf16x8*)(&At[cur][(wr * 32 + f * 16 + lrow) * 64 + ((ks * 4 + lk) ^ sx) * 8]);
#pragma unroll
      for (int f = 0; f < 4; f++)
        bfr[f][ks] = *(const bf16x8*)(&Bt[cur][(wc * 64 + f * 16 + lrow) * 64 + ((ks * 4 + lk) ^ sx) * 8]);
    }
    asm volatile("s_waitcnt lgkmcnt(0)" ::: "memory");
    __builtin_amdgcn_sched_barrier(0);
    __builtin_amdgcn_s_barrier();
    if (t + 2 < nt) stage((t + 2) * 64, cur);
    __builtin_amdgcn_sched_barrier(0);
    __builtin_amdgcn_s_setprio(1);
#pragma unroll
    for (int ks = 0; ks < 2; ks++)
#pragma unroll
      for (int fr = 0; fr < 2; fr++)
#pragma unroll
        for (int fc = 0; fc < 4; fc++)
          acc[fr][fc] = __builtin_amdgcn_mfma_f32_16x16x32_bf16(afr[fr][ks], bfr[fc][ks], acc[fr][fc], 0, 0, 0);
    __builtin_amdgcn_s_setprio(0);
  }

  // epilogue: out[token] += acc + p*b2   (exactly 2 atomic addends per element -> deterministic)
#pragma unroll
  for (int fr = 0; fr < 2; fr++) {
#pragma unroll
    for (int reg = 0; reg < 4; reg++) {
      const int rloc = wr * 32 + fr * 16 + lk * 4 + reg;
      const int grow = rbase + rloc;
      if (grow < cnt) {
        const int slot = slot_list[e * CAP + grow];
        const float p  = prob_list[e * CAP + grow];
        float* dst = out + (size_t)(slot >> 1) * D_DIM + n0 + wc * 64 + lrow;
#pragma unroll
        for (int fc = 0; fc < 4; fc++) {
          float v = acc[fr][fc][reg] + p * b2[e * D_DIM + n0 + wc * 64 + fc * 16 + lrow];
          atomicAdd(&dst[fc * 16], v);
        }
      }
    }
  }
}

extern "C" void kernel_launch(void* const* d_in, const int* in_sizes, int n_in,
                              void* d_out, int out_size, void* d_ws, size_t ws_size,
                              hipStream_t stream) {
  const float* x  = (const float*)d_in[0];
  const float* w1 = (const float*)d_in[1];
  const float* w2 = (const float*)d_in[2];
  const float* b1 = (const float*)d_in[3];
  const float* b2 = (const float*)d_in[4];
  const float* rw = (const float*)d_in[5];
  const float* rb = (const float*)d_in[6];
  float* out = (float*)d_out;

  char* ws = (char*)d_ws;
  size_t off = 0;
  auto alloc = [&](size_t bytes) -> void* {
    void* p = ws + off;
    off = (off + bytes + 255) & ~(size_t)255;
    return p;
  };
  int*   counts    = (int*)alloc(E_NUM * 4);
  int*   slot_list = (int*)alloc((size_t)E_NUM * CAP * 4);
  float* prob_list = (float*)alloc((size_t)E_NUM * CAP * 4);
  int*   topk_idx  = (int*)alloc((size_t)T_TOKENS * 2 * 4);
  float* topk_p    = (float*)alloc((size_t)T_TOKENS * 2 * 4);
  u16*   xb        = (u16*)alloc((size_t)T_TOKENS * D_DIM * 2);
  u16*   w1t       = (u16*)alloc((size_t)E_NUM * H_DIM * D_DIM * 2);
  u16*   w2t       = (u16*)alloc((size_t)E_NUM * H_DIM * D_DIM * 2);
  u16*   hbuf      = (u16*)alloc((size_t)NSLOT * H_DIM * 2);

  transpose_both_kernel<<<4096, 256, 0, stream>>>(w1, w2, w1t, w2t);
  router_kernel<<<T_TOKENS / 4, 256, 0, stream>>>(x, rw, rb, topk_idx, topk_p, xb, out);
  compact_kernel<<<E_NUM, 256, 0, stream>>>(topk_idx, topk_p, slot_list, prob_list, counts);
  gemm1_kernel<<<dim3(H_DIM / 128, E_NUM * 32), 256, 0, stream>>>(xb, w1t, b1, slot_list, prob_list, counts, hbuf);
  gemm2_kernel<<<dim3(D_DIM / 128, E_NUM * 64), 256, 0, stream>>>(hbuf, w2t, b2, slot_list, prob_list, counts, out);
}